// Round 9
// baseline (312.492 us; speedup 1.0000x reference)
//
#include <hip/hip_runtime.h>
#include <hip/hip_bf16.h>
#include <stdint.h>

// GatedScreeningTile: B=2 N=2048 DIM=2048 H=16 DK=64 DV=128 DIM_INNER=3072
// Pipeline: cvt/transpose -> GEMM3(qg|kv) -> normalize -> fused attn -> GEMM3(out)
// GEMM3: grid=256 exact (1 block/CU), 8 waves, BK=32, TRIPLE-buffered LDS,
// ONE barrier per K-tile, counted vmcnt (loads always in flight until tail).

typedef unsigned short u16;
typedef __bf16 bf16x8 __attribute__((ext_vector_type(8)));
typedef u16 u16x8 __attribute__((ext_vector_type(8)));
typedef float f32x4 __attribute__((ext_vector_type(4)));
typedef float f32x16 __attribute__((ext_vector_type(16)));
typedef int i32x4 __attribute__((ext_vector_type(4)));

#define DEVINL __device__ __forceinline__

DEVINL u16 f2bf(float f) {
  union { float f; uint32_t u; } v; v.f = f;
  uint32_t r = (v.u + 0x7FFFu + ((v.u >> 16) & 1u)) >> 16;
  return (u16)r;
}
DEVINL float bf2f(u16 x) {
  union { uint32_t u; float f; } v; v.u = ((uint32_t)x) << 16;
  return v.f;
}
DEVINL bf16x8 as_bf(u16x8 v) { return __builtin_bit_cast(bf16x8, v); }

typedef const __attribute__((address_space(1))) uint32_t* gptr_t;
typedef __attribute__((address_space(3))) uint32_t* lptr_t;
DEVINL void gload_lds16(const void* g, void* l) {
  __builtin_amdgcn_global_load_lds((gptr_t)g, (lptr_t)l, 16, 0, 0);
}

DEVINL f32x4 mfma16(u16x8 a, u16x8 b, f32x4 c) {
  return __builtin_amdgcn_mfma_f32_16x16x32_bf16(as_bf(a), as_bf(b), c, 0, 0, 0);
}
DEVINL f32x16 mfma32(u16x8 a, u16x8 b, f32x16 c) {
  return __builtin_amdgcn_mfma_f32_32x32x16_bf16(as_bf(a), as_bf(b), c, 0, 0, 0);
}

// ---------------- fp32 -> bf16 convert (same layout) ----------------
__global__ void k_cvt(const float* __restrict__ src, u16* __restrict__ dst, int n) {
  int i = (blockIdx.x * blockDim.x + threadIdx.x) * 4;
  int stride = gridDim.x * blockDim.x * 4;
  for (; i < n; i += stride) {
    float4 f = *(const float4*)(src + i);
    ushort4 o;
    o.x = f2bf(f.x); o.y = f2bf(f.y); o.z = f2bf(f.z); o.w = f2bf(f.w);
    *(ushort4*)(dst + i) = o;
  }
}

// ---------------- fp32 (RxC) -> bf16 transposed (CxR) ----------------
__global__ void k_cvtT(const float* __restrict__ src, u16* __restrict__ dst, int R, int C) {
  __shared__ float tile[32][33];
  int c0 = blockIdx.x * 32, r0 = blockIdx.y * 32;
  int tc = threadIdx.x & 31, tr = threadIdx.x >> 5;  // tr 0..7
#pragma unroll
  for (int i = 0; i < 4; i++) {
    int r = tr + i * 8;
    tile[r][tc] = src[(size_t)(r0 + r) * C + c0 + tc];
  }
  __syncthreads();
#pragma unroll
  for (int i = 0; i < 4; i++) {
    int r = tr + i * 8;  // row in dst tile (= src col)
    dst[(size_t)(c0 + r) * R + r0 + tc] = f2bf(tile[tc][r]);
  }
}

// ---------------- GEMM3: C(MxNt) = A(MxK) * Bt(NtxK)^T, grid MUST be 256 ----------------
// BK=32; 512 thr = 8 waves (2 x 4), wave tile WM x WN. Triple-buffered LDS
// ([3][BM][32] A + [3][BN][32] B u16), granule-swizzled: LDS[row][g] holds
// global[row][g ^ ((row>>1)&3)] (16B granules; inverse applied on gload source).
// Per K-tile: {vmcnt(NLD) | vmcnt(0) at tail; lgkmcnt(0); s_barrier} then
// stage(t+2) -> slot[(t+2)%3], then frag reads + MI*NI MFMA. Loads from
// stage(t+1) remain in flight across the barrier (counted-vmcnt, T3/T4).
template <int BM, int BN, int WM, int WN, int F32OUT>
__global__ __launch_bounds__(512, 1) void k_gemm3(const u16* __restrict__ A,
                                                  const u16* __restrict__ Bt,
                                                  void* __restrict__ Cout,
                                                  int M, int Nt, int K) {
  constexpr int MI = WM / 16, NI = WN / 16;
  constexpr int NA = BM / 128, NB = BN / 128;   // gloads per wave per tile
  constexpr int ABUF = BM * 32, BBUF = BN * 32; // u16 per slot
  extern __shared__ char smem[];
  u16* As = (u16*)smem;                    // [3][BM][32]
  u16* Bs = (u16*)(smem + 3 * ABUF * 2);   // [3][BN][32]

  const int tid = threadIdx.x, lane = tid & 63, wid = tid >> 6;

  // XCD-aware block remap: grid=256, xcd = bid&7 owns (Nt/BN)/8 n-panels x all m.
  const int NBM = M / BM, NBN = Nt / BN;
  const int bid = blockIdx.x;
  const int xcd = bid & 7, idx = bid >> 3;  // idx 0..31
  const int m0 = (idx % NBM) * BM;
  const int n0 = (xcd * (NBN / 8) + idx / NBM) * BN;

  const int wm = (wid >> 2) * WM, wn = (wid & 3) * WN;
  const int fr = lane & 15, hi = lane >> 4, frow = hi * 4;
  const int gsw = (hi ^ ((fr >> 1) & 3)) << 3;  // frag-read granule (u16 units)

  f32x4 acc[MI][NI] = {};

  // staging lane constants: load i covers rows base16 = wid*16*N_ + i*16;
  // lane -> row base16 + (lane>>2), src granule (lane&3) ^ ((lane>>3)&3).
  const int sgran = (((lane & 3) ^ ((lane >> 3) & 3))) << 3;
  const u16* gA0 = A + (size_t)(m0 + wid * 16 * NA + (lane >> 2)) * K + sgran;
  const u16* gB0 = Bt + (size_t)(n0 + wid * 16 * NB + (lane >> 2)) * K + sgran;
  const int adst = wid * 16 * NA * 32;  // u16, wave-uniform
  const int bdst = wid * 16 * NB * 32;
  const size_t r16 = (size_t)16 * K;

#define STAGE(T, S)                                                                  \
  {                                                                                  \
    const int kt_ = (T) * 32;                                                        \
    _Pragma("unroll") for (int i = 0; i < NA; i++)                                   \
        gload_lds16(gA0 + (size_t)i * r16 + kt_, As + (S)*ABUF + adst + i * 512);    \
    _Pragma("unroll") for (int i = 0; i < NB; i++)                                   \
        gload_lds16(gB0 + (size_t)i * r16 + kt_, Bs + (S)*BBUF + bdst + i * 512);    \
  }

  STAGE(0, 0);
  STAGE(1, 1);

  const int NTI = K >> 5;
  int slot = 0;
  for (int t = 0; t < NTI; t++) {
    if (t < NTI - 1) {
      if constexpr (NA + NB == 5) asm volatile("s_waitcnt vmcnt(5)" ::: "memory");
      else asm volatile("s_waitcnt vmcnt(3)" ::: "memory");
    } else {
      asm volatile("s_waitcnt vmcnt(0)" ::: "memory");
    }
    asm volatile("s_waitcnt lgkmcnt(0)" ::: "memory");
    __builtin_amdgcn_s_barrier();
    asm volatile("" ::: "memory");

    if (t + 2 < NTI) {
      const int s2 = (slot + 2 >= 3) ? slot - 1 : slot + 2;
      STAGE(t + 2, s2);
    }

    const u16* Ab = As + slot * ABUF;
    const u16* Bb = Bs + slot * BBUF;
    u16x8 af[MI], bf[NI];
#pragma unroll
    for (int mi = 0; mi < MI; mi++)
      af[mi] = *(const u16x8*)(Ab + (wm + mi * 16 + fr) * 32 + gsw);
#pragma unroll
    for (int ni = 0; ni < NI; ni++)
      bf[ni] = *(const u16x8*)(Bb + (wn + ni * 16 + fr) * 32 + gsw);

    __builtin_amdgcn_s_setprio(1);
#pragma unroll
    for (int mi = 0; mi < MI; mi++)
#pragma unroll
      for (int ni = 0; ni < NI; ni++)
        acc[mi][ni] = mfma16(af[mi], bf[ni], acc[mi][ni]);
    __builtin_amdgcn_s_setprio(0);

    slot = (slot + 1 >= 3) ? 0 : slot + 1;
  }
#undef STAGE

#pragma unroll
  for (int mi = 0; mi < MI; mi++)
#pragma unroll
    for (int ni = 0; ni < NI; ni++)
#pragma unroll
      for (int j = 0; j < 4; j++) {
        const size_t row = m0 + wm + mi * 16 + frow + j;
        const size_t col = n0 + wn + ni * 16 + fr;
        if (F32OUT) ((float*)Cout)[row * Nt + col] = acc[mi][ni][j];
        else ((u16*)Cout)[row * Nt + col] = f2bf(acc[mi][ni][j]);
      }
}

// ---------------- normalize: qgkv raw -> qn, kn, vnT, gact ----------------
// vnT stored with sigma-permuted columns within each 32-n group (swap bits 2,3)
// so that attn's PV A-fragment k-order matches the in-register P^T B-fragment.
__global__ __launch_bounds__(256, 4) void k_norm(const u16* __restrict__ qgkv,
                                                 u16* __restrict__ qn, u16* __restrict__ kn,
                                                 u16* __restrict__ vnT, u16* __restrict__ gact) {
  __shared__ u16 vt[128 * 64];  // [d][nl], col swizzle: c' = nl ^ ((d&15)<<2)
  const int tid = threadIdx.x, lane = tid & 63, wid = tid >> 6;
  const int hb = blockIdx.y;            // b*16 + h
  const int h = hb & 15, b = hb >> 4;
  const int n0 = blockIdx.x * 64;

  for (int s = 0; s < 16; s++) {
    const int nl = wid * 16 + s;        // 0..63
    const int n = n0 + nl;
    const size_t bn = (size_t)b * 2048 + n;
    const size_t baseq = bn * 6144 + (size_t)h * 192;
    const size_t basek = baseq + 3072;

    float q = bf2f(qgkv[baseq + lane]);
    float g0 = bf2f(qgkv[baseq + 64 + lane]);
    float g1 = bf2f(qgkv[baseq + 128 + lane]);
    float k = bf2f(qgkv[basek + lane]);
    float v0 = bf2f(qgkv[basek + 64 + lane]);
    float v1 = bf2f(qgkv[basek + 128 + lane]);

    float qs = q * q, ks = k * k, vs = v0 * v0 + v1 * v1;
#pragma unroll
    for (int m = 1; m < 64; m <<= 1) {
      qs += __shfl_xor(qs, m);
      ks += __shfl_xor(ks, m);
      vs += __shfl_xor(vs, m);
    }
    float rq = 1.f / fmaxf(sqrtf(qs), 1e-12f);
    float rk = 1.f / fmaxf(sqrtf(ks), 1e-12f);
    float rv = 1.f / fmaxf(sqrtf(vs), 1e-12f);

    qn[((size_t)hb * 2048 + n) * 64 + lane] = f2bf(q * rq);
    kn[((size_t)hb * 2048 + n) * 64 + lane] = f2bf(k * rk);
    float s0 = g0 / (1.f + __expf(-g0));
    float s1 = g1 / (1.f + __expf(-g1));
    gact[((size_t)hb * 2048 + n) * 128 + lane] = f2bf(tanhf(s0));
    gact[((size_t)hb * 2048 + n) * 128 + 64 + lane] = f2bf(tanhf(s1));

    const int d0 = lane, d1 = 64 + lane;
    vt[d0 * 64 + (nl ^ ((d0 & 15) << 2))] = f2bf(v0 * rv);
    vt[d1 * 64 + (nl ^ ((d1 & 15) << 2))] = f2bf(v1 * rv);
  }
  __syncthreads();

  // write-out: sigma(col) = swap bits 2<->3 within n&31 (preserves bits 0-1)
#pragma unroll
  for (int p = 0; p < 8; p++) {
    const int d = p * 16 + (tid >> 4);
    const int nq = (tid & 15) * 4;
    const int cb = nq ^ ((d & 15) << 2);
    const int nq2 = (nq & ~12) | ((nq & 4) << 1) | ((nq & 8) >> 1);
    ushort4 o;
    o.x = vt[d * 64 + cb + 0];
    o.y = vt[d * 64 + cb + 1];
    o.z = vt[d * 64 + cb + 2];
    o.w = vt[d * 64 + cb + 3];
    *(ushort4*)(vnT + ((size_t)hb * 128 + d) * 2048 + n0 + nq2) = o;
  }
}

// ---------------- fused screened attention (swapped-operand 32x32, P in registers) ----------------
__global__ __launch_bounds__(256, 2) void k_attn(const u16* __restrict__ qn,
                                                 const u16* __restrict__ kn,
                                                 const u16* __restrict__ vnT,
                                                 const u16* __restrict__ gact,
                                                 const float* __restrict__ ls_iaw,
                                                 const float* __restrict__ ls_hws,
                                                 u16* __restrict__ pre_out) {
  extern __shared__ char smem[];
  u16* KsB = (u16*)smem;                 // [2][64 k][64 dk]  8KB each
  u16* VsB = (u16*)(smem + 16384);       // [2][128 d][64 k'] 16KB each (k' sigma-order)
  u16* Os = (u16*)smem;                  // epilogue reuse: [128 q][132 d] 33.8KB

  const int tid = threadIdx.x, lane = tid & 63, wid = tid >> 6;
  const int bid = blockIdx.y * 16 + blockIdx.x;
  const int bh = (bid & 7) * 4 + ((bid >> 3) & 3);
  const int n0 = (bid >> 5) * 128;
  const int h = bh & 15;
  const int l31 = lane & 31, L = lane >> 5, rb = l31 & 7;
  const float r = 1.f / (__expf(ls_iaw[h]) + 1.f);
  const float c1 = 1.f - r;
  const float whs = __expf(ls_hws[h]);

  const int wq = wid * 32;
  const u16* qrow = qn + ((size_t)bh * 2048 + n0 + wq + l31) * 64;
  u16x8 qf[4];
#pragma unroll
  for (int c = 0; c < 4; c++) qf[c] = *(const u16x8*)(qrow + c * 16 + L * 8);

  f32x16 acc[4] = {};  // acc[dt]: D[d = dt*32 + (reg&3)+8*(reg>>2)+4L][q = l31]
  const u16* kbase = kn + (size_t)bh * 2048 * 64;
  const u16* vbase = vnT + (size_t)bh * 128 * 2048;

  int ks_goff[2];
#pragma unroll
  for (int i = 0; i < 2; i++) {
    int row = wid * 16 + i * 8 + (lane >> 3);
    ks_goff[i] = row * 64 + (((lane & 7) ^ (row & 7)) << 3);
  }
  int vs_goff[4];
#pragma unroll
  for (int i = 0; i < 4; i++) {
    int row = wid * 32 + i * 8 + (lane >> 3);
    vs_goff[i] = row * 2048 + (((lane & 7) ^ (row & 7)) << 3);
  }

  {
    u16* KsC = KsB + wid * 1024;
    u16* VsC = VsB + wid * 2048;
#pragma unroll
    for (int i = 0; i < 2; i++) gload_lds16(kbase + ks_goff[i], KsC + i * 512);
#pragma unroll
    for (int i = 0; i < 4; i++) gload_lds16(vbase + vs_goff[i], VsC + i * 512);
  }

  int cur = 0;
  for (int t = 0; t < 32; t++) {
    asm volatile("s_waitcnt vmcnt(0) lgkmcnt(0)" ::: "memory");
    __builtin_amdgcn_s_barrier();
    asm volatile("" ::: "memory");

    if (t < 31) {
      const int kv0 = (t + 1) * 64;
      u16* KsC2 = KsB + (cur ^ 1) * 4096 + wid * 1024;
      u16* VsC2 = VsB + (cur ^ 1) * 8192 + wid * 2048;
#pragma unroll
      for (int i = 0; i < 2; i++) gload_lds16(kbase + (size_t)kv0 * 64 + ks_goff[i], KsC2 + i * 512);
#pragma unroll
      for (int i = 0; i < 4; i++) gload_lds16(vbase + (size_t)vs_goff[i] + kv0, VsC2 + i * 512);
    }

    const u16* KsC = KsB + cur * 4096;
    const u16* VsC = VsB + cur * 8192;

    f32x16 sT0 = {}, sT1 = {};
    __builtin_amdgcn_s_setprio(1);
#pragma unroll
    for (int c = 0; c < 4; c++) {
      u16x8 kf0 = *(const u16x8*)(KsC + (0 + l31) * 64 + (((2 * c + L) ^ rb) << 3));
      u16x8 kf1 = *(const u16x8*)(KsC + (32 + l31) * 64 + (((2 * c + L) ^ rb) << 3));
      sT0 = mfma32(kf0, qf[c], sT0);
      sT1 = mfma32(kf1, qf[c], sT1);
    }
    __builtin_amdgcn_s_setprio(0);

    uint32_t w[2][4][2];
#pragma unroll
    for (int m = 0; m < 4; m++)
#pragma unroll
      for (int p = 0; p < 2; p++) {
        float a0 = fmaxf(0.f, fmaf(r, sT0[4 * m + 2 * p], c1));
        float a1 = fmaxf(0.f, fmaf(r, sT0[4 * m + 2 * p + 1], c1));
        float b0 = fmaxf(0.f, fmaf(r, sT1[4 * m + 2 * p], c1));
        float b1 = fmaxf(0.f, fmaf(r, sT1[4 * m + 2 * p + 1], c1));
        w[0][m][p] = (uint32_t)f2bf(a0 * a0) | ((uint32_t)f2bf(a1 * a1) << 16);
        w[1][m][p] = (uint32_t)f2bf(b0 * b0) | ((uint32_t)f2bf(b1 * b1) << 16);
      }

    __builtin_amdgcn_s_setprio(1);
#pragma unroll
    for (int kt = 0; kt < 2; kt++)
#pragma unroll
      for (int pair = 0; pair < 2; pair++) {
        i32x4 pw;
        pw[0] = (int)w[kt][2 * pair][0];
        pw[1] = (int)w[kt][2 * pair][1];
        pw[2] = (int)w[kt][2 * pair + 1][0];
        pw[3] = (int)w[kt][2 * pair + 1][1];
        u16x8 pf = __builtin_bit_cast(u16x8, pw);
        const int chunk = 4 * kt + 2 * pair + L;
#pragma unroll
        for (int dt = 0; dt < 4; dt++) {
          u16x8 vf = *(const u16x8*)(VsC + (dt * 32 + l31) * 64 + ((chunk ^ rb) << 3));
          acc[dt] = mfma32(vf, pf, acc[dt]);
        }
      }
    __builtin_amdgcn_s_setprio(0);
    cur ^= 1;
  }

  float ss = 0.f;
#pragma unroll
  for (int dt = 0; dt < 4; dt++)
#pragma unroll
    for (int e = 0; e < 16; e++) { float x = acc[dt][e]; ss += x * x; }
  ss += __shfl_xor(ss, 32);
  float nn = sqrtf(ss);
  float scale = tanhf(nn) / fmaxf(nn, 1e-12f) * whs;

  __syncthreads();

  const int q = wq + l31;
  const size_t grow = ((size_t)bh * 2048 + n0 + q) * 128;
#pragma unroll
  for (int dt = 0; dt < 4; dt++)
#pragma unroll
    for (int m = 0; m < 4; m++) {
      const int d = dt * 32 + 8 * m + 4 * L;
      ushort4 gv = *(const ushort4*)(gact + grow + d);
      ushort4 o;
      o.x = f2bf(acc[dt][4 * m + 0] * scale * bf2f(gv.x));
      o.y = f2bf(acc[dt][4 * m + 1] * scale * bf2f(gv.y));
      o.z = f2bf(acc[dt][4 * m + 2] * scale * bf2f(gv.z));
      o.w = f2bf(acc[dt][4 * m + 3] * scale * bf2f(gv.w));
      *(ushort4*)(Os + q * 132 + d) = o;
    }
  __syncthreads();

  const int orow = tid >> 1, oc0 = (tid & 1) * 64;
  const size_t obase = ((size_t)(bh >> 4) * 2048 + n0 + orow) * 2048 + (size_t)h * 128 + oc0;
#pragma unroll
  for (int j = 0; j < 16; j++) {
    ushort4 v = *(const ushort4*)(Os + orow * 132 + oc0 + 4 * j);
    *(ushort4*)(pre_out + obase + 4 * j) = v;
  }
}

extern "C" void kernel_launch(void* const* d_in, const int* in_sizes, int n_in,
                              void* d_out, int out_size, void* d_ws, size_t ws_size,
                              hipStream_t stream) {
  (void)in_sizes; (void)n_in; (void)out_size; (void)ws_size;
  const float* tokens = (const float*)d_in[0];
  const float* Wqg = (const float*)d_in[1];
  const float* Wkv = (const float*)d_in[2];
  const float* Wo = (const float*)d_in[3];
  const float* ls_iaw = (const float*)d_in[4];
  const float* ls_hws = (const float*)d_in[5];
  float* out = (float*)d_out;
  char* ws = (char*)d_ws;

  // workspace layout (phased aliasing, total 109 MB):
  u16* WoT = (u16*)(ws + 0);                     // 8,388,608 B
  char* regA = ws + 8388608;                     // 50,331,648 B
  u16* tok_bf = (u16*)(regA);                    // phase A-B (16.8MB)
  u16* WqgkvT = (u16*)(regA + 16777216);         // phase A-B (25.2MB) [6144][2048]
  u16* qn = (u16*)(regA);                        // phase C-D
  u16* kn = (u16*)(regA + 8388608);
  u16* vnT = (u16*)(regA + 16777216);
  u16* gact = (u16*)(regA + 33554432);
  char* regB = ws + 58720256;                    // 50,331,648 B
  u16* qgkv_raw = (u16*)(regB);                  // phase B-C [4096][6144]
  u16* pre_out = (u16*)(regB);                   // phase D-E

  k_cvt<<<4096, 256, 0, stream>>>(tokens, tok_bf, 8388608);
  k_cvtT<<<dim3(96, 64), 256, 0, stream>>>(Wqg, WqgkvT, 2048, 3072);
  k_cvtT<<<dim3(96, 64), 256, 0, stream>>>(Wkv, WqgkvT + (size_t)3072 * 2048, 2048, 3072);
  k_cvtT<<<dim3(64, 64), 256, 0, stream>>>(Wo, WoT, 2048, 2048);

  // merged projection: 256x384 tile, grid 16x16=256, LDS 3*(256+384)*32*2 = 120KB
  k_gemm3<256, 384, 128, 96, 0><<<256, 512, 122880, stream>>>(tok_bf, WqgkvT, qgkv_raw, 4096, 6144, 2048);

  k_norm<<<dim3(32, 32), 256, 0, stream>>>(qgkv_raw, qn, kn, vnT, gact);

  k_attn<<<dim3(16, 32), 256, 49152, stream>>>(qn, kn, vnT, gact, ls_iaw, ls_hws, pre_out);

  // final projection: 128x256 tile, grid 32x8=256, LDS 3*(128+256)*32*2 = 72KB
  k_gemm3<128, 256, 64, 64, 1><<<256, 512, 73728, stream>>>(pre_out, WoT, out, 4096, 2048, 2048);
}

// Round 10
// 286.499 us; speedup vs baseline: 1.0907x; 1.0907x over previous
//
#include <hip/hip_runtime.h>
#include <hip/hip_bf16.h>
#include <stdint.h>

// GatedScreeningTile: B=2 N=2048 DIM=2048 H=16 DK=64 DV=128 DIM_INNER=3072
// Pipeline: cvt/transpose -> k_gemmP(qg|kv) -> normalize -> fused attn -> k_gemm3(out)
// k_gemmP: 128x384 tile, BK=64, grid 512 = 2 EXACT rounds of 256 CUs, 8 waves,
// 4 quadrant phases/tile with counted vmcnt (R8's verified schedule, re-derived
// for the 8-load [A0,B0,B1,B2,A1,B3,B4,B5] stage order).

typedef unsigned short u16;
typedef __bf16 bf16x8 __attribute__((ext_vector_type(8)));
typedef u16 u16x8 __attribute__((ext_vector_type(8)));
typedef float f32x4 __attribute__((ext_vector_type(4)));
typedef float f32x16 __attribute__((ext_vector_type(16)));
typedef int i32x4 __attribute__((ext_vector_type(4)));

#define DEVINL __device__ __forceinline__

DEVINL u16 f2bf(float f) {
  union { float f; uint32_t u; } v; v.f = f;
  uint32_t r = (v.u + 0x7FFFu + ((v.u >> 16) & 1u)) >> 16;
  return (u16)r;
}
DEVINL float bf2f(u16 x) {
  union { uint32_t u; float f; } v; v.u = ((uint32_t)x) << 16;
  return v.f;
}
DEVINL bf16x8 as_bf(u16x8 v) { return __builtin_bit_cast(bf16x8, v); }

typedef const __attribute__((address_space(1))) uint32_t* gptr_t;
typedef __attribute__((address_space(3))) uint32_t* lptr_t;
DEVINL void gload_lds16(const void* g, void* l) {
  __builtin_amdgcn_global_load_lds((gptr_t)g, (lptr_t)l, 16, 0, 0);
}

DEVINL f32x4 mfma16(u16x8 a, u16x8 b, f32x4 c) {
  return __builtin_amdgcn_mfma_f32_16x16x32_bf16(as_bf(a), as_bf(b), c, 0, 0, 0);
}
DEVINL f32x16 mfma32(u16x8 a, u16x8 b, f32x16 c) {
  return __builtin_amdgcn_mfma_f32_32x32x16_bf16(as_bf(a), as_bf(b), c, 0, 0, 0);
}

// ---------------- fp32 -> bf16 convert (same layout) ----------------
__global__ void k_cvt(const float* __restrict__ src, u16* __restrict__ dst, int n) {
  int i = (blockIdx.x * blockDim.x + threadIdx.x) * 4;
  int stride = gridDim.x * blockDim.x * 4;
  for (; i < n; i += stride) {
    float4 f = *(const float4*)(src + i);
    ushort4 o;
    o.x = f2bf(f.x); o.y = f2bf(f.y); o.z = f2bf(f.z); o.w = f2bf(f.w);
    *(ushort4*)(dst + i) = o;
  }
}

// ---------------- fp32 (RxC) -> bf16 transposed (CxR) ----------------
__global__ void k_cvtT(const float* __restrict__ src, u16* __restrict__ dst, int R, int C) {
  __shared__ float tile[32][33];
  int c0 = blockIdx.x * 32, r0 = blockIdx.y * 32;
  int tc = threadIdx.x & 31, tr = threadIdx.x >> 5;  // tr 0..7
#pragma unroll
  for (int i = 0; i < 4; i++) {
    int r = tr + i * 8;
    tile[r][tc] = src[(size_t)(r0 + r) * C + c0 + tc];
  }
  __syncthreads();
#pragma unroll
  for (int i = 0; i < 4; i++) {
    int r = tr + i * 8;  // row in dst tile (= src col)
    dst[(size_t)(c0 + r) * R + r0 + tc] = f2bf(tile[tc][r]);
  }
}

// ---------------- k_gemmP: merged projection, 128x384, BK=64, 4-phase counted vmcnt ----------------
// Quadrants: (MH,NH) MH-half=64 rows, NH-half=192 cols. Wave (2m x 4n):
// mq32=(wid>>2)*32, nq48=(wid&3)*48 -> per quad MI=2, NI=3 (12 MFMA, 10 ds_reads).
// LDS [2][128][64]A + [2][384][64]B = 128KB, XOR-swizzled (granule ^= row&7, inverse
// pre-swizzle on global source). Stage order per tile: A0,B0,B1,B2,A1,B3,B4,B5.
template <int MH, int NH>
DEVINL void kp_quad(const u16* __restrict__ Ab, const u16* __restrict__ Bb,
                    f32x4 (&acc)[2][2][2][3], int mq32, int nq48,
                    int fr, int hi, int rb7) {
  u16x8 af[2][2], bf[3][2];
#pragma unroll
  for (int mi = 0; mi < 2; mi++)
#pragma unroll
    for (int kk = 0; kk < 2; kk++) {
      const int row = MH * 64 + mq32 + mi * 16 + fr;
      af[mi][kk] = *(const u16x8*)(Ab + row * 64 + (((kk * 4 + hi) ^ rb7) << 3));
    }
#pragma unroll
  for (int ni = 0; ni < 3; ni++)
#pragma unroll
    for (int kk = 0; kk < 2; kk++) {
      const int row = NH * 192 + nq48 + ni * 16 + fr;
      bf[ni][kk] = *(const u16x8*)(Bb + row * 64 + (((kk * 4 + hi) ^ rb7) << 3));
    }
  __builtin_amdgcn_s_setprio(1);
#pragma unroll
  for (int kk = 0; kk < 2; kk++)
#pragma unroll
    for (int mi = 0; mi < 2; mi++)
#pragma unroll
      for (int ni = 0; ni < 3; ni++)
        acc[MH][mi][NH][ni] = mfma16(af[mi][kk], bf[ni][kk], acc[MH][mi][NH][ni]);
  __builtin_amdgcn_s_setprio(0);
}

__global__ __launch_bounds__(512, 1) void k_gemmP(const u16* __restrict__ A,
                                                  const u16* __restrict__ Bt,
                                                  u16* __restrict__ C,
                                                  int Nt, int K) {
  extern __shared__ char smem[];
  u16* As = (u16*)smem;             // [2][128][64]  ABUF=8192 u16
  u16* Bs = (u16*)(smem + 32768);   // [2][384][64]  BBUF=24576 u16
  const int tid = threadIdx.x, lane = tid & 63, wid = tid >> 6;

  // XCD remap: grid 512 = 32 m-panels x 16 n-panels; xcd owns 2 n-panels (B slice 3MB -> L2)
  const int bid = blockIdx.x;
  const int xcd = bid & 7, idx = bid >> 3;  // idx 0..63
  const int m0 = (idx & 31) * 128;
  const int n0 = (xcd * 2 + (idx >> 5)) * 384;

  const int mq32 = (wid >> 2) * 32, nq48 = (wid & 3) * 48;
  const int fr = lane & 15, hi = lane >> 4, frow = hi * 4, rb7 = fr & 7;

  f32x4 acc[2][2][2][3] = {};

  // staging: line = 64 rows; wave wid covers rows wid*8..+8 of each line;
  // lane -> row wid*8 + (lane>>3), src granule (lane&7)^((lane>>3)&7) [= row&7 key]
  const int schunk = ((lane & 7) ^ ((lane >> 3) & 7)) << 3;
  const int srow = wid * 8 + (lane >> 3);
  const u16* ga0 = A + (size_t)(m0 + srow) * K + schunk;
  const u16* gb0 = Bt + (size_t)(n0 + srow) * K + schunk;
  const size_t l64 = (size_t)64 * K;
  const int dwave = wid * 512;  // u16, wave-uniform

#define SA(P, L, KT) gload_lds16(ga0 + (size_t)(L) * l64 + (KT), As + (P) * 8192 + (L) * 4096 + dwave)
#define SB(P, L, KT) gload_lds16(gb0 + (size_t)(L) * l64 + (KT), Bs + (P) * 24576 + (L) * 4096 + dwave)

  // prologue: tile 0 -> buf 0, order A0, B0,B1,B2, A1, B3,B4,B5
  SA(0, 0, 0); SB(0, 0, 0); SB(0, 1, 0); SB(0, 2, 0);
  SA(0, 1, 0); SB(0, 3, 0); SB(0, 4, 0); SB(0, 5, 0);

  const int NTI = K >> 6;  // 32
  for (int t = 0; t < NTI; t++) {
    const int p = t & 1, pn = p ^ 1;
    const int ktn = (t < NTI - 1 ? t + 1 : t) << 6;  // clamped (tail re-stage harmless)
    const u16* Ab = As + p * 8192;
    const u16* Bb = Bs + p * 24576;

    // P1 (MH0,NH0): needs A l0 + B l0..2 = oldest 4 of 8 outstanding
    asm volatile("s_waitcnt vmcnt(4)" ::: "memory");
    __builtin_amdgcn_s_barrier();
    asm volatile("" ::: "memory");
    SA(pn, 0, ktn); SB(pn, 0, ktn);
    kp_quad<0, 0>(Ab, Bb, acc, mq32, nq48, fr, hi, rb7);

    // P2 (MH1,NH0): needs A l1 (5th oldest; 6 outstanding -> retire 1)
    asm volatile("s_waitcnt vmcnt(5)" ::: "memory");
    __builtin_amdgcn_s_barrier();
    asm volatile("" ::: "memory");
    SB(pn, 1, ktn); SB(pn, 2, ktn);
    kp_quad<1, 0>(Ab, Bb, acc, mq32, nq48, fr, hi, rb7);

    // P3 (MH0,NH1): needs B l3..5 (oldest 3 of 7 -> retire 3)
    asm volatile("s_waitcnt vmcnt(4)" ::: "memory");
    __builtin_amdgcn_s_barrier();
    asm volatile("" ::: "memory");
    SA(pn, 1, ktn); SB(pn, 3, ktn);
    kp_quad<0, 1>(Ab, Bb, acc, mq32, nq48, fr, hi, rb7);

    // P4 (MH1,NH1): everything already waited; no wait/barrier
    SB(pn, 4, ktn); SB(pn, 5, ktn);
    kp_quad<1, 1>(Ab, Bb, acc, mq32, nq48, fr, hi, rb7);
  }
#undef SA
#undef SB
  asm volatile("s_waitcnt vmcnt(0)" ::: "memory");  // drain tail re-stage before exit

#pragma unroll
  for (int mh = 0; mh < 2; mh++)
#pragma unroll
    for (int mi = 0; mi < 2; mi++)
#pragma unroll
      for (int nh = 0; nh < 2; nh++)
#pragma unroll
        for (int ni = 0; ni < 3; ni++)
#pragma unroll
          for (int j = 0; j < 4; j++) {
            const size_t row = m0 + mh * 64 + mq32 + mi * 16 + frow + j;
            const size_t col = n0 + nh * 192 + nq48 + ni * 16 + fr;
            C[row * Nt + col] = f2bf(acc[mh][mi][nh][ni][j]);
          }
}

// ---------------- k_gemm3: final projection (grid 256, triple-buffer, counted vmcnt) ----------------
template <int BM, int BN, int WM, int WN, int F32OUT>
__global__ __launch_bounds__(512, 1) void k_gemm3(const u16* __restrict__ A,
                                                  const u16* __restrict__ Bt,
                                                  void* __restrict__ Cout,
                                                  int M, int Nt, int K) {
  constexpr int MI = WM / 16, NI = WN / 16;
  constexpr int NA = BM / 128, NB = BN / 128;
  constexpr int ABUF = BM * 32, BBUF = BN * 32;
  extern __shared__ char smem[];
  u16* As = (u16*)smem;
  u16* Bs = (u16*)(smem + 3 * ABUF * 2);

  const int tid = threadIdx.x, lane = tid & 63, wid = tid >> 6;

  const int NBM = M / BM, NBN = Nt / BN;
  const int bid = blockIdx.x;
  const int xcd = bid & 7, idx = bid >> 3;
  const int m0 = (idx % NBM) * BM;
  const int n0 = (xcd * (NBN / 8) + idx / NBM) * BN;

  const int wm = (wid >> 2) * WM, wn = (wid & 3) * WN;
  const int fr = lane & 15, hi = lane >> 4, frow = hi * 4;
  const int gsw = (hi ^ ((fr >> 1) & 3)) << 3;

  f32x4 acc[MI][NI] = {};

  const int sgran = (((lane & 3) ^ ((lane >> 3) & 3))) << 3;
  const u16* gA0 = A + (size_t)(m0 + wid * 16 * NA + (lane >> 2)) * K + sgran;
  const u16* gB0 = Bt + (size_t)(n0 + wid * 16 * NB + (lane >> 2)) * K + sgran;
  const int adst = wid * 16 * NA * 32;
  const int bdst = wid * 16 * NB * 32;
  const size_t r16 = (size_t)16 * K;

#define STAGE(T, S)                                                                  \
  {                                                                                  \
    const int kt_ = (T) * 32;                                                        \
    _Pragma("unroll") for (int i = 0; i < NA; i++)                                   \
        gload_lds16(gA0 + (size_t)i * r16 + kt_, As + (S)*ABUF + adst + i * 512);    \
    _Pragma("unroll") for (int i = 0; i < NB; i++)                                   \
        gload_lds16(gB0 + (size_t)i * r16 + kt_, Bs + (S)*BBUF + bdst + i * 512);    \
  }

  STAGE(0, 0);
  STAGE(1, 1);

  const int NTI = K >> 5;
  int slot = 0;
  for (int t = 0; t < NTI; t++) {
    if (t < NTI - 1) {
      if constexpr (NA + NB == 5) asm volatile("s_waitcnt vmcnt(5)" ::: "memory");
      else asm volatile("s_waitcnt vmcnt(3)" ::: "memory");
    } else {
      asm volatile("s_waitcnt vmcnt(0)" ::: "memory");
    }
    asm volatile("s_waitcnt lgkmcnt(0)" ::: "memory");
    __builtin_amdgcn_s_barrier();
    asm volatile("" ::: "memory");

    if (t + 2 < NTI) {
      const int s2 = (slot + 2 >= 3) ? slot - 1 : slot + 2;
      STAGE(t + 2, s2);
    }

    const u16* Ab = As + slot * ABUF;
    const u16* Bb = Bs + slot * BBUF;
    u16x8 af[MI], bf[NI];
#pragma unroll
    for (int mi = 0; mi < MI; mi++)
      af[mi] = *(const u16x8*)(Ab + (wm + mi * 16 + fr) * 32 + gsw);
#pragma unroll
    for (int ni = 0; ni < NI; ni++)
      bf[ni] = *(const u16x8*)(Bb + (wn + ni * 16 + fr) * 32 + gsw);

    __builtin_amdgcn_s_setprio(1);
#pragma unroll
    for (int mi = 0; mi < MI; mi++)
#pragma unroll
      for (int ni = 0; ni < NI; ni++)
        acc[mi][ni] = mfma16(af[mi], bf[ni], acc[mi][ni]);
    __builtin_amdgcn_s_setprio(0);

    slot = (slot + 1 >= 3) ? 0 : slot + 1;
  }
#undef STAGE

#pragma unroll
  for (int mi = 0; mi < MI; mi++)
#pragma unroll
    for (int ni = 0; ni < NI; ni++)
#pragma unroll
      for (int j = 0; j < 4; j++) {
        const size_t row = m0 + wm + mi * 16 + frow + j;
        const size_t col = n0 + wn + ni * 16 + fr;
        if (F32OUT) ((float*)Cout)[row * Nt + col] = acc[mi][ni][j];
        else ((u16*)Cout)[row * Nt + col] = f2bf(acc[mi][ni][j]);
      }
}

// ---------------- normalize: qgkv raw -> qn, kn, vnT, gact ----------------
__global__ __launch_bounds__(256, 4) void k_norm(const u16* __restrict__ qgkv,
                                                 u16* __restrict__ qn, u16* __restrict__ kn,
                                                 u16* __restrict__ vnT, u16* __restrict__ gact) {
  __shared__ u16 vt[128 * 64];  // [d][nl], col swizzle: c' = nl ^ ((d&15)<<2)
  const int tid = threadIdx.x, lane = tid & 63, wid = tid >> 6;
  const int hb = blockIdx.y;            // b*16 + h
  const int h = hb & 15, b = hb >> 4;
  const int n0 = blockIdx.x * 64;

  for (int s = 0; s < 16; s++) {
    const int nl = wid * 16 + s;        // 0..63
    const int n = n0 + nl;
    const size_t bn = (size_t)b * 2048 + n;
    const size_t baseq = bn * 6144 + (size_t)h * 192;
    const size_t basek = baseq + 3072;

    float q = bf2f(qgkv[baseq + lane]);
    float g0 = bf2f(qgkv[baseq + 64 + lane]);
    float g1 = bf2f(qgkv[baseq + 128 + lane]);
    float k = bf2f(qgkv[basek + lane]);
    float v0 = bf2f(qgkv[basek + 64 + lane]);
    float v1 = bf2f(qgkv[basek + 128 + lane]);

    float qs = q * q, ks = k * k, vs = v0 * v0 + v1 * v1;
#pragma unroll
    for (int m = 1; m < 64; m <<= 1) {
      qs += __shfl_xor(qs, m);
      ks += __shfl_xor(ks, m);
      vs += __shfl_xor(vs, m);
    }
    float rq = 1.f / fmaxf(sqrtf(qs), 1e-12f);
    float rk = 1.f / fmaxf(sqrtf(ks), 1e-12f);
    float rv = 1.f / fmaxf(sqrtf(vs), 1e-12f);

    qn[((size_t)hb * 2048 + n) * 64 + lane] = f2bf(q * rq);
    kn[((size_t)hb * 2048 + n) * 64 + lane] = f2bf(k * rk);
    float s0 = g0 / (1.f + __expf(-g0));
    float s1 = g1 / (1.f + __expf(-g1));
    gact[((size_t)hb * 2048 + n) * 128 + lane] = f2bf(tanhf(s0));
    gact[((size_t)hb * 2048 + n) * 128 + 64 + lane] = f2bf(tanhf(s1));

    const int d0 = lane, d1 = 64 + lane;
    vt[d0 * 64 + (nl ^ ((d0 & 15) << 2))] = f2bf(v0 * rv);
    vt[d1 * 64 + (nl ^ ((d1 & 15) << 2))] = f2bf(v1 * rv);
  }
  __syncthreads();

  // write-out: sigma(col) = swap bits 2<->3 within n&31 (preserves bits 0-1)
#pragma unroll
  for (int p = 0; p < 8; p++) {
    const int d = p * 16 + (tid >> 4);
    const int nq = (tid & 15) * 4;
    const int cb = nq ^ ((d & 15) << 2);
    const int nq2 = (nq & ~12) | ((nq & 4) << 1) | ((nq & 8) >> 1);
    ushort4 o;
    o.x = vt[d * 64 + cb + 0];
    o.y = vt[d * 64 + cb + 1];
    o.z = vt[d * 64 + cb + 2];
    o.w = vt[d * 64 + cb + 3];
    *(ushort4*)(vnT + ((size_t)hb * 128 + d) * 2048 + n0 + nq2) = o;
  }
}

// ---------------- fused screened attention (swapped-operand 32x32, P in registers) ----------------
__global__ __launch_bounds__(256, 2) void k_attn(const u16* __restrict__ qn,
                                                 const u16* __restrict__ kn,
                                                 const u16* __restrict__ vnT,
                                                 const u16* __restrict__ gact,
                                                 const float* __restrict__ ls_iaw,
                                                 const float* __restrict__ ls_hws,
                                                 u16* __restrict__ pre_out) {
  extern __shared__ char smem[];
  u16* KsB = (u16*)smem;                 // [2][64 k][64 dk]  8KB each
  u16* VsB = (u16*)(smem + 16384);       // [2][128 d][64 k'] 16KB each (k' sigma-order)
  u16* Os = (u16*)smem;                  // epilogue reuse: [128 q][132 d] 33.8KB

  const int tid = threadIdx.x, lane = tid & 63, wid = tid >> 6;
  const int bid = blockIdx.y * 16 + blockIdx.x;
  const int bh = (bid & 7) * 4 + ((bid >> 3) & 3);
  const int n0 = (bid >> 5) * 128;
  const int h = bh & 15;
  const int l31 = lane & 31, L = lane >> 5, rb = l31 & 7;
  const float r = 1.f / (__expf(ls_iaw[h]) + 1.f);
  const float c1 = 1.f - r;
  const float whs = __expf(ls_hws[h]);

  const int wq = wid * 32;
  const u16* qrow = qn + ((size_t)bh * 2048 + n0 + wq + l31) * 64;
  u16x8 qf[4];
#pragma unroll
  for (int c = 0; c < 4; c++) qf[c] = *(const u16x8*)(qrow + c * 16 + L * 8);

  f32x16 acc[4] = {};  // acc[dt]: D[d = dt*32 + (reg&3)+8*(reg>>2)+4L][q = l31]
  const u16* kbase = kn + (size_t)bh * 2048 * 64;
  const u16* vbase = vnT + (size_t)bh * 128 * 2048;

  int ks_goff[2];
#pragma unroll
  for (int i = 0; i < 2; i++) {
    int row = wid * 16 + i * 8 + (lane >> 3);
    ks_goff[i] = row * 64 + (((lane & 7) ^ (row & 7)) << 3);
  }
  int vs_goff[4];
#pragma unroll
  for (int i = 0; i < 4; i++) {
    int row = wid * 32 + i * 8 + (lane >> 3);
    vs_goff[i] = row * 2048 + (((lane & 7) ^ (row & 7)) << 3);
  }

  {
    u16* KsC = KsB + wid * 1024;
    u16* VsC = VsB + wid * 2048;
#pragma unroll
    for (int i = 0; i < 2; i++) gload_lds16(kbase + ks_goff[i], KsC + i * 512);
#pragma unroll
    for (int i = 0; i < 4; i++) gload_lds16(vbase + vs_goff[i], VsC + i * 512);
  }

  int cur = 0;
  for (int t = 0; t < 32; t++) {
    asm volatile("s_waitcnt vmcnt(0) lgkmcnt(0)" ::: "memory");
    __builtin_amdgcn_s_barrier();
    asm volatile("" ::: "memory");

    if (t < 31) {
      const int kv0 = (t + 1) * 64;
      u16* KsC2 = KsB + (cur ^ 1) * 4096 + wid * 1024;
      u16* VsC2 = VsB + (cur ^ 1) * 8192 + wid * 2048;
#pragma unroll
      for (int i = 0; i < 2; i++) gload_lds16(kbase + (size_t)kv0 * 64 + ks_goff[i], KsC2 + i * 512);
#pragma unroll
      for (int i = 0; i < 4; i++) gload_lds16(vbase + (size_t)vs_goff[i] + kv0, VsC2 + i * 512);
    }

    const u16* KsC = KsB + cur * 4096;
    const u16* VsC = VsB + cur * 8192;

    f32x16 sT0 = {}, sT1 = {};
    __builtin_amdgcn_s_setprio(1);
#pragma unroll
    for (int c = 0; c < 4; c++) {
      u16x8 kf0 = *(const u16x8*)(KsC + (0 + l31) * 64 + (((2 * c + L) ^ rb) << 3));
      u16x8 kf1 = *(const u16x8*)(KsC + (32 + l31) * 64 + (((2 * c + L) ^ rb) << 3));
      sT0 = mfma32(kf0, qf[c], sT0);
      sT1 = mfma32(kf1, qf[c], sT1);
    }
    __builtin_amdgcn_s_setprio(0);

    uint32_t w[2][4][2];
#pragma unroll
    for (int m = 0; m < 4; m++)
#pragma unroll
      for (int p = 0; p < 2; p++) {
        float a0 = fmaxf(0.f, fmaf(r, sT0[4 * m + 2 * p], c1));
        float a1 = fmaxf(0.f, fmaf(r, sT0[4 * m + 2 * p + 1], c1));
        float b0 = fmaxf(0.f, fmaf(r, sT1[4 * m + 2 * p], c1));
        float b1 = fmaxf(0.f, fmaf(r, sT1[4 * m + 2 * p + 1], c1));
        w[0][m][p] = (uint32_t)f2bf(a0 * a0) | ((uint32_t)f2bf(a1 * a1) << 16);
        w[1][m][p] = (uint32_t)f2bf(b0 * b0) | ((uint32_t)f2bf(b1 * b1) << 16);
      }

    __builtin_amdgcn_s_setprio(1);
#pragma unroll
    for (int kt = 0; kt < 2; kt++)
#pragma unroll
      for (int pair = 0; pair < 2; pair++) {
        i32x4 pw;
        pw[0] = (int)w[kt][2 * pair][0];
        pw[1] = (int)w[kt][2 * pair][1];
        pw[2] = (int)w[kt][2 * pair + 1][0];
        pw[3] = (int)w[kt][2 * pair + 1][1];
        u16x8 pf = __builtin_bit_cast(u16x8, pw);
        const int chunk = 4 * kt + 2 * pair + L;
#pragma unroll
        for (int dt = 0; dt < 4; dt++) {
          u16x8 vf = *(const u16x8*)(VsC + (dt * 32 + l31) * 64 + ((chunk ^ rb) << 3));
          acc[dt] = mfma32(vf, pf, acc[dt]);
        }
      }
    __builtin_amdgcn_s_setprio(0);
    cur ^= 1;
  }

  float ss = 0.f;
#pragma unroll
  for (int dt = 0; dt < 4; dt++)
#pragma unroll
    for (int e = 0; e < 16; e++) { float x = acc[dt][e]; ss += x * x; }
  ss += __shfl_xor(ss, 32);
  float nn = sqrtf(ss);
  float scale = tanhf(nn) / fmaxf(nn, 1e-12f) * whs;

  __syncthreads();

  const int q = wq + l31;
  const size_t grow = ((size_t)bh * 2048 + n0 + q) * 128;
#pragma unroll
  for (int dt = 0; dt < 4; dt++)
#pragma unroll
    for (int m = 0; m < 4; m++) {
      const int d = dt * 32 + 8 * m + 4 * L;
      ushort4 gv = *(const ushort4*)(gact + grow + d);
      ushort4 o;
      o.x = f2bf(acc[dt][4 * m + 0] * scale * bf2f(gv.x));
      o.y = f2bf(acc[dt][4 * m + 1] * scale * bf2f(gv.y));
      o.z = f2bf(acc[dt][4 * m + 2] * scale * bf2f(gv.z));
      o.w = f2bf(acc[dt][4 * m + 3] * scale * bf2f(gv.w));
      *(ushort4*)(Os + q * 132 + d) = o;
    }
  __syncthreads();

  const int orow = tid >> 1, oc0 = (tid & 1) * 64;
  const size_t obase = ((size_t)(bh >> 4) * 2048 + n0 + orow) * 2048 + (size_t)h * 128 + oc0;
#pragma unroll
  for (int j = 0; j < 16; j++) {
    ushort4 v = *(const ushort4*)(Os + orow * 132 + oc0 + 4 * j);
    *(ushort4*)(pre_out + obase + 4 * j) = v;
  }
}

extern "C" void kernel_launch(void* const* d_in, const int* in_sizes, int n_in,
                              void* d_out, int out_size, void* d_ws, size_t ws_size,
                              hipStream_t stream) {
  (void)in_sizes; (void)n_in; (void)out_size; (void)ws_size;
  const float* tokens = (const float*)d_in[0];
  const float* Wqg = (const float*)d_in[1];
  const float* Wkv = (const float*)d_in[2];
  const float* Wo = (const float*)d_in[3];
  const float* ls_iaw = (const float*)d_in[4];
  const float* ls_hws = (const float*)d_in[5];
  float* out = (float*)d_out;
  char* ws = (char*)d_ws;

  // workspace layout (phased aliasing, total 109 MB):
  u16* WoT = (u16*)(ws + 0);                     // 8,388,608 B
  char* regA = ws + 8388608;                     // 50,331,648 B
  u16* tok_bf = (u16*)(regA);                    // phase A-B (16.8MB)
  u16* WqgkvT = (u16*)(regA + 16777216);         // phase A-B (25.2MB) [6144][2048]
  u16* qn = (u16*)(regA);                        // phase C-D
  u16* kn = (u16*)(regA + 8388608);
  u16* vnT = (u16*)(regA + 16777216);
  u16* gact = (u16*)(regA + 33554432);
  char* regB = ws + 58720256;                    // 50,331,648 B
  u16* qgkv_raw = (u16*)(regB);                  // phase B-C [4096][6144]
  u16* pre_out = (u16*)(regB);                   // phase D-E

  k_cvt<<<4096, 256, 0, stream>>>(tokens, tok_bf, 8388608);
  k_cvtT<<<dim3(96, 64), 256, 0, stream>>>(Wqg, WqgkvT, 2048, 3072);
  k_cvtT<<<dim3(96, 64), 256, 0, stream>>>(Wkv, WqgkvT + (size_t)3072 * 2048, 2048, 3072);
  k_cvtT<<<dim3(64, 64), 256, 0, stream>>>(Wo, WoT, 2048, 2048);

  // merged projection: 128x384 tile, grid 512 = 2 exact rounds, 128KB LDS
  k_gemmP<<<512, 512, 131072, stream>>>(tok_bf, WqgkvT, qgkv_raw, 6144, 2048);

  k_norm<<<dim3(32, 32), 256, 0, stream>>>(qgkv_raw, qn, kn, vnT, gact);

  k_attn<<<dim3(16, 32), 256, 49152, stream>>>(qn, kn, vnT, gact, ls_iaw, ls_hws, pre_out);

  // final projection: 128x256 tile, grid 32x8=256, LDS 3*(128+256)*32*2 = 72KB
  k_gemm3<128, 256, 64, 64, 1><<<256, 512, 73728, stream>>>(pre_out, WoT, out, 4096, 2048, 2048);
}

// Round 11
// 272.275 us; speedup vs baseline: 1.1477x; 1.0522x over previous
//
#include <hip/hip_runtime.h>
#include <hip/hip_bf16.h>
#include <stdint.h>

// GatedScreeningTile: B=2 N=2048 DIM=2048 H=16 DK=64 DV=128 DIM_INNER=3072
// Pipeline: cvt/transpose -> k_gemmU<3>(qg|kv) -> normalize -> fused attn -> k_gemmU<2>(out)
// k_gemmU: BM=128, BN=NI*128, BK=64; 8 waves (2m x 4n); ONE barrier per K-tile;
// ALL unique fragments read once into registers (no quadrant re-reads); stage(t+1)
// issued right after the tile barrier and drained by the NEXT tile's vmcnt(0)
// (a full compute-tile of distance, so HBM latency is covered).

typedef unsigned short u16;
typedef __bf16 bf16x8 __attribute__((ext_vector_type(8)));
typedef u16 u16x8 __attribute__((ext_vector_type(8)));
typedef float f32x4 __attribute__((ext_vector_type(4)));
typedef float f32x16 __attribute__((ext_vector_type(16)));
typedef int i32x4 __attribute__((ext_vector_type(4)));

#define DEVINL __device__ __forceinline__

DEVINL u16 f2bf(float f) {
  union { float f; uint32_t u; } v; v.f = f;
  uint32_t r = (v.u + 0x7FFFu + ((v.u >> 16) & 1u)) >> 16;
  return (u16)r;
}
DEVINL float bf2f(u16 x) {
  union { uint32_t u; float f; } v; v.u = ((uint32_t)x) << 16;
  return v.f;
}
DEVINL bf16x8 as_bf(u16x8 v) { return __builtin_bit_cast(bf16x8, v); }

typedef const __attribute__((address_space(1))) uint32_t* gptr_t;
typedef __attribute__((address_space(3))) uint32_t* lptr_t;
DEVINL void gload_lds16(const void* g, void* l) {
  __builtin_amdgcn_global_load_lds((gptr_t)g, (lptr_t)l, 16, 0, 0);
}

DEVINL f32x4 mfma16(u16x8 a, u16x8 b, f32x4 c) {
  return __builtin_amdgcn_mfma_f32_16x16x32_bf16(as_bf(a), as_bf(b), c, 0, 0, 0);
}
DEVINL f32x16 mfma32(u16x8 a, u16x8 b, f32x16 c) {
  return __builtin_amdgcn_mfma_f32_32x32x16_bf16(as_bf(a), as_bf(b), c, 0, 0, 0);
}

// ---------------- fp32 -> bf16 convert (same layout) ----------------
__global__ void k_cvt(const float* __restrict__ src, u16* __restrict__ dst, int n) {
  int i = (blockIdx.x * blockDim.x + threadIdx.x) * 4;
  int stride = gridDim.x * blockDim.x * 4;
  for (; i < n; i += stride) {
    float4 f = *(const float4*)(src + i);
    ushort4 o;
    o.x = f2bf(f.x); o.y = f2bf(f.y); o.z = f2bf(f.z); o.w = f2bf(f.w);
    *(ushort4*)(dst + i) = o;
  }
}

// ---------------- fp32 (RxC) -> bf16 transposed (CxR) ----------------
__global__ void k_cvtT(const float* __restrict__ src, u16* __restrict__ dst, int R, int C) {
  __shared__ float tile[32][33];
  int c0 = blockIdx.x * 32, r0 = blockIdx.y * 32;
  int tc = threadIdx.x & 31, tr = threadIdx.x >> 5;  // tr 0..7
#pragma unroll
  for (int i = 0; i < 4; i++) {
    int r = tr + i * 8;
    tile[r][tc] = src[(size_t)(r0 + r) * C + c0 + tc];
  }
  __syncthreads();
#pragma unroll
  for (int i = 0; i < 4; i++) {
    int r = tr + i * 8;  // row in dst tile (= src col)
    dst[(size_t)(c0 + r) * R + r0 + tc] = f2bf(tile[tc][r]);
  }
}

// ---------------- k_gemmU: unified GEMM, single barrier per K-tile ----------------
// C(4096 x Nt) = A(4096 x K) * Bt(Nt x K)^T.  BM=128, BN=NI*128, BK=64.
// LDS [2][128][64]A + [2][BN][64]B, XOR-swizzled (granule ^= row&7; inverse
// pre-swizzle on global source, R10-verified conflict-free). Grid must be
// 32*(Nt/BN): NI=3 -> 512 (2 exact CU rounds), NI=2 -> 256 (1 exact round).
template <int NI, int F32OUT>
__global__ __launch_bounds__(512, 1) void k_gemmU(const u16* __restrict__ A,
                                                  const u16* __restrict__ Bt,
                                                  void* __restrict__ Cout,
                                                  int Nt, int K) {
  constexpr int BN = NI * 128;
  constexpr int NLB = BN / 64;            // B lines of 64 rows
  constexpr int ABUF = 128 * 64;          // u16 per slot
  constexpr int BBUF = BN * 64;
  extern __shared__ char smem[];
  u16* As = (u16*)smem;                   // [2][128][64]
  u16* Bs = (u16*)(smem + 2 * ABUF * 2);  // [2][BN][64]

  const int tid = threadIdx.x, lane = tid & 63, wid = tid >> 6;

  // XCD remap: xcd = bid&7 owns (Nt/BN)/8 n-panels x all 32 m-panels
  const int NPN = Nt / BN;
  const int bid = blockIdx.x;
  const int xcd = bid & 7, idx = bid >> 3;
  const int npx = NPN >> 3;
  const int m0 = (idx & 31) * 128;
  const int n0 = (xcd * npx + (idx >> 5)) * BN;

  const int mq = (wid >> 2) * 32, nq = (wid & 3) * (BN / 8);
  const int fr = lane & 15, hi = lane >> 4, frow = hi * 4, rb7 = fr & 7;

  f32x4 acc[2][2][2][NI] = {};

  // staging lane constants (inverse swizzle on global source; linear LDS dest)
  const int schunk = ((lane & 7) ^ ((lane >> 3) & 7)) << 3;
  const int srow = wid * 8 + (lane >> 3);
  const u16* ga0 = A + (size_t)(m0 + srow) * K + schunk;
  const u16* gb0 = Bt + (size_t)(n0 + srow) * K + schunk;
  const size_t l64 = (size_t)64 * K;
  const int dwave = wid * 512;  // u16, wave-uniform

#define STG(T, P)                                                                     \
  {                                                                                   \
    const int kt_ = (T) << 6;                                                         \
    _Pragma("unroll") for (int i = 0; i < 2; i++)                                     \
        gload_lds16(ga0 + (size_t)i * l64 + kt_, As + (P) * ABUF + i * 4096 + dwave); \
    _Pragma("unroll") for (int i = 0; i < NLB; i++)                                   \
        gload_lds16(gb0 + (size_t)i * l64 + kt_, Bs + (P) * BBUF + i * 4096 + dwave); \
  }

  STG(0, 0);

  const int NTI = K >> 6;
  for (int t = 0; t < NTI; t++) {
    // tile t landed (its loads were issued one full compute-tile ago)
    asm volatile("s_waitcnt vmcnt(0) lgkmcnt(0)" ::: "memory");
    __builtin_amdgcn_s_barrier();
    asm volatile("" ::: "memory");

    const int p = t & 1;
    if (t + 1 < NTI) STG(t + 1, p ^ 1);  // in flight across this whole tile

    const u16* Ab = As + p * ABUF;
    const u16* Bb = Bs + p * BBUF;

    // read ALL unique fragments once (no quadrant re-reads)
    u16x8 af[2][2][2], bf[2][NI][2];
#pragma unroll
    for (int MH = 0; MH < 2; MH++)
#pragma unroll
      for (int mi = 0; mi < 2; mi++)
#pragma unroll
        for (int kk = 0; kk < 2; kk++) {
          const int row = MH * 64 + mq + mi * 16 + fr;
          af[MH][mi][kk] = *(const u16x8*)(Ab + row * 64 + (((kk * 4 + hi) ^ rb7) << 3));
        }
#pragma unroll
    for (int NH = 0; NH < 2; NH++)
#pragma unroll
      for (int ni = 0; ni < NI; ni++)
#pragma unroll
        for (int kk = 0; kk < 2; kk++) {
          const int row = NH * (BN / 2) + nq + ni * 16 + fr;
          bf[NH][ni][kk] = *(const u16x8*)(Bb + row * 64 + (((kk * 4 + hi) ^ rb7) << 3));
        }

    __builtin_amdgcn_s_setprio(1);
#pragma unroll
    for (int kk = 0; kk < 2; kk++)
#pragma unroll
      for (int MH = 0; MH < 2; MH++)
#pragma unroll
        for (int mi = 0; mi < 2; mi++)
#pragma unroll
          for (int NH = 0; NH < 2; NH++)
#pragma unroll
            for (int ni = 0; ni < NI; ni++)
              acc[MH][mi][NH][ni] = mfma16(af[MH][mi][kk], bf[NH][ni][kk], acc[MH][mi][NH][ni]);
    __builtin_amdgcn_s_setprio(0);
  }
#undef STG

#pragma unroll
  for (int MH = 0; MH < 2; MH++)
#pragma unroll
    for (int mi = 0; mi < 2; mi++)
#pragma unroll
      for (int NH = 0; NH < 2; NH++)
#pragma unroll
        for (int ni = 0; ni < NI; ni++)
#pragma unroll
          for (int j = 0; j < 4; j++) {
            const size_t row = m0 + MH * 64 + mq + mi * 16 + frow + j;
            const size_t col = n0 + NH * (BN / 2) + nq + ni * 16 + fr;
            if (F32OUT) ((float*)Cout)[row * Nt + col] = acc[MH][mi][NH][ni][j];
            else ((u16*)Cout)[row * Nt + col] = f2bf(acc[MH][mi][NH][ni][j]);
          }
}

// ---------------- normalize: qgkv raw -> qn, kn, vnT, gact ----------------
__global__ __launch_bounds__(256, 4) void k_norm(const u16* __restrict__ qgkv,
                                                 u16* __restrict__ qn, u16* __restrict__ kn,
                                                 u16* __restrict__ vnT, u16* __restrict__ gact) {
  __shared__ u16 vt[128 * 64];  // [d][nl], col swizzle: c' = nl ^ ((d&15)<<2)
  const int tid = threadIdx.x, lane = tid & 63, wid = tid >> 6;
  const int hb = blockIdx.y;            // b*16 + h
  const int h = hb & 15, b = hb >> 4;
  const int n0 = blockIdx.x * 64;

  for (int s = 0; s < 16; s++) {
    const int nl = wid * 16 + s;        // 0..63
    const int n = n0 + nl;
    const size_t bn = (size_t)b * 2048 + n;
    const size_t baseq = bn * 6144 + (size_t)h * 192;
    const size_t basek = baseq + 3072;

    float q = bf2f(qgkv[baseq + lane]);
    float g0 = bf2f(qgkv[baseq + 64 + lane]);
    float g1 = bf2f(qgkv[baseq + 128 + lane]);
    float k = bf2f(qgkv[basek + lane]);
    float v0 = bf2f(qgkv[basek + 64 + lane]);
    float v1 = bf2f(qgkv[basek + 128 + lane]);

    float qs = q * q, ks = k * k, vs = v0 * v0 + v1 * v1;
#pragma unroll
    for (int m = 1; m < 64; m <<= 1) {
      qs += __shfl_xor(qs, m);
      ks += __shfl_xor(ks, m);
      vs += __shfl_xor(vs, m);
    }
    float rq = 1.f / fmaxf(sqrtf(qs), 1e-12f);
    float rk = 1.f / fmaxf(sqrtf(ks), 1e-12f);
    float rv = 1.f / fmaxf(sqrtf(vs), 1e-12f);

    qn[((size_t)hb * 2048 + n) * 64 + lane] = f2bf(q * rq);
    kn[((size_t)hb * 2048 + n) * 64 + lane] = f2bf(k * rk);
    float s0 = g0 / (1.f + __expf(-g0));
    float s1 = g1 / (1.f + __expf(-g1));
    gact[((size_t)hb * 2048 + n) * 128 + lane] = f2bf(tanhf(s0));
    gact[((size_t)hb * 2048 + n) * 128 + 64 + lane] = f2bf(tanhf(s1));

    const int d0 = lane, d1 = 64 + lane;
    vt[d0 * 64 + (nl ^ ((d0 & 15) << 2))] = f2bf(v0 * rv);
    vt[d1 * 64 + (nl ^ ((d1 & 15) << 2))] = f2bf(v1 * rv);
  }
  __syncthreads();

  // write-out: sigma(col) = swap bits 2<->3 within n&31 (preserves bits 0-1)
#pragma unroll
  for (int p = 0; p < 8; p++) {
    const int d = p * 16 + (tid >> 4);
    const int nq = (tid & 15) * 4;
    const int cb = nq ^ ((d & 15) << 2);
    const int nq2 = (nq & ~12) | ((nq & 4) << 1) | ((nq & 8) >> 1);
    ushort4 o;
    o.x = vt[d * 64 + cb + 0];
    o.y = vt[d * 64 + cb + 1];
    o.z = vt[d * 64 + cb + 2];
    o.w = vt[d * 64 + cb + 3];
    *(ushort4*)(vnT + ((size_t)hb * 128 + d) * 2048 + n0 + nq2) = o;
  }
}

// ---------------- fused screened attention (swapped-operand 32x32, P in registers) ----------------
__global__ __launch_bounds__(256, 2) void k_attn(const u16* __restrict__ qn,
                                                 const u16* __restrict__ kn,
                                                 const u16* __restrict__ vnT,
                                                 const u16* __restrict__ gact,
                                                 const float* __restrict__ ls_iaw,
                                                 const float* __restrict__ ls_hws,
                                                 u16* __restrict__ pre_out) {
  extern __shared__ char smem[];
  u16* KsB = (u16*)smem;                 // [2][64 k][64 dk]  8KB each
  u16* VsB = (u16*)(smem + 16384);       // [2][128 d][64 k'] 16KB each (k' sigma-order)
  u16* Os = (u16*)smem;                  // epilogue reuse: [128 q][132 d] 33.8KB

  const int tid = threadIdx.x, lane = tid & 63, wid = tid >> 6;
  const int bid = blockIdx.y * 16 + blockIdx.x;
  const int bh = (bid & 7) * 4 + ((bid >> 3) & 3);
  const int n0 = (bid >> 5) * 128;
  const int h = bh & 15;
  const int l31 = lane & 31, L = lane >> 5, rb = l31 & 7;
  const float r = 1.f / (__expf(ls_iaw[h]) + 1.f);
  const float c1 = 1.f - r;
  const float whs = __expf(ls_hws[h]);

  const int wq = wid * 32;
  const u16* qrow = qn + ((size_t)bh * 2048 + n0 + wq + l31) * 64;
  u16x8 qf[4];
#pragma unroll
  for (int c = 0; c < 4; c++) qf[c] = *(const u16x8*)(qrow + c * 16 + L * 8);

  f32x16 acc[4] = {};  // acc[dt]: D[d = dt*32 + (reg&3)+8*(reg>>2)+4L][q = l31]
  const u16* kbase = kn + (size_t)bh * 2048 * 64;
  const u16* vbase = vnT + (size_t)bh * 128 * 2048;

  int ks_goff[2];
#pragma unroll
  for (int i = 0; i < 2; i++) {
    int row = wid * 16 + i * 8 + (lane >> 3);
    ks_goff[i] = row * 64 + (((lane & 7) ^ (row & 7)) << 3);
  }
  int vs_goff[4];
#pragma unroll
  for (int i = 0; i < 4; i++) {
    int row = wid * 32 + i * 8 + (lane >> 3);
    vs_goff[i] = row * 2048 + (((lane & 7) ^ (row & 7)) << 3);
  }

  {
    u16* KsC = KsB + wid * 1024;
    u16* VsC = VsB + wid * 2048;
#pragma unroll
    for (int i = 0; i < 2; i++) gload_lds16(kbase + ks_goff[i], KsC + i * 512);
#pragma unroll
    for (int i = 0; i < 4; i++) gload_lds16(vbase + vs_goff[i], VsC + i * 512);
  }

  int cur = 0;
  for (int t = 0; t < 32; t++) {
    asm volatile("s_waitcnt vmcnt(0) lgkmcnt(0)" ::: "memory");
    __builtin_amdgcn_s_barrier();
    asm volatile("" ::: "memory");

    if (t < 31) {
      const int kv0 = (t + 1) * 64;
      u16* KsC2 = KsB + (cur ^ 1) * 4096 + wid * 1024;
      u16* VsC2 = VsB + (cur ^ 1) * 8192 + wid * 2048;
#pragma unroll
      for (int i = 0; i < 2; i++) gload_lds16(kbase + (size_t)kv0 * 64 + ks_goff[i], KsC2 + i * 512);
#pragma unroll
      for (int i = 0; i < 4; i++) gload_lds16(vbase + (size_t)vs_goff[i] + kv0, VsC2 + i * 512);
    }

    const u16* KsC = KsB + cur * 4096;
    const u16* VsC = VsB + cur * 8192;

    f32x16 sT0 = {}, sT1 = {};
    __builtin_amdgcn_s_setprio(1);
#pragma unroll
    for (int c = 0; c < 4; c++) {
      u16x8 kf0 = *(const u16x8*)(KsC + (0 + l31) * 64 + (((2 * c + L) ^ rb) << 3));
      u16x8 kf1 = *(const u16x8*)(KsC + (32 + l31) * 64 + (((2 * c + L) ^ rb) << 3));
      sT0 = mfma32(kf0, qf[c], sT0);
      sT1 = mfma32(kf1, qf[c], sT1);
    }
    __builtin_amdgcn_s_setprio(0);

    uint32_t w[2][4][2];
#pragma unroll
    for (int m = 0; m < 4; m++)
#pragma unroll
      for (int p = 0; p < 2; p++) {
        float a0 = fmaxf(0.f, fmaf(r, sT0[4 * m + 2 * p], c1));
        float a1 = fmaxf(0.f, fmaf(r, sT0[4 * m + 2 * p + 1], c1));
        float b0 = fmaxf(0.f, fmaf(r, sT1[4 * m + 2 * p], c1));
        float b1 = fmaxf(0.f, fmaf(r, sT1[4 * m + 2 * p + 1], c1));
        w[0][m][p] = (uint32_t)f2bf(a0 * a0) | ((uint32_t)f2bf(a1 * a1) << 16);
        w[1][m][p] = (uint32_t)f2bf(b0 * b0) | ((uint32_t)f2bf(b1 * b1) << 16);
      }

    __builtin_amdgcn_s_setprio(1);
#pragma unroll
    for (int kt = 0; kt < 2; kt++)
#pragma unroll
      for (int pair = 0; pair < 2; pair++) {
        i32x4 pw;
        pw[0] = (int)w[kt][2 * pair][0];
        pw[1] = (int)w[kt][2 * pair][1];
        pw[2] = (int)w[kt][2 * pair + 1][0];
        pw[3] = (int)w[kt][2 * pair + 1][1];
        u16x8 pf = __builtin_bit_cast(u16x8, pw);
        const int chunk = 4 * kt + 2 * pair + L;
#pragma unroll
        for (int dt = 0; dt < 4; dt++) {
          u16x8 vf = *(const u16x8*)(VsC + (dt * 32 + l31) * 64 + ((chunk ^ rb) << 3));
          acc[dt] = mfma32(vf, pf, acc[dt]);
        }
      }
    __builtin_amdgcn_s_setprio(0);
    cur ^= 1;
  }

  float ss = 0.f;
#pragma unroll
  for (int dt = 0; dt < 4; dt++)
#pragma unroll
    for (int e = 0; e < 16; e++) { float x = acc[dt][e]; ss += x * x; }
  ss += __shfl_xor(ss, 32);
  float nn = sqrtf(ss);
  float scale = tanhf(nn) / fmaxf(nn, 1e-12f) * whs;

  __syncthreads();

  const int q = wq + l31;
  const size_t grow = ((size_t)bh * 2048 + n0 + q) * 128;
#pragma unroll
  for (int dt = 0; dt < 4; dt++)
#pragma unroll
    for (int m = 0; m < 4; m++) {
      const int d = dt * 32 + 8 * m + 4 * L;
      ushort4 gv = *(const ushort4*)(gact + grow + d);
      ushort4 o;
      o.x = f2bf(acc[dt][4 * m + 0] * scale * bf2f(gv.x));
      o.y = f2bf(acc[dt][4 * m + 1] * scale * bf2f(gv.y));
      o.z = f2bf(acc[dt][4 * m + 2] * scale * bf2f(gv.z));
      o.w = f2bf(acc[dt][4 * m + 3] * scale * bf2f(gv.w));
      *(ushort4*)(Os + q * 132 + d) = o;
    }
  __syncthreads();

  const int orow = tid >> 1, oc0 = (tid & 1) * 64;
  const size_t obase = ((size_t)(bh >> 4) * 2048 + n0 + orow) * 2048 + (size_t)h * 128 + oc0;
#pragma unroll
  for (int j = 0; j < 16; j++) {
    ushort4 v = *(const ushort4*)(Os + orow * 132 + oc0 + 4 * j);
    *(ushort4*)(pre_out + obase + 4 * j) = v;
  }
}

extern "C" void kernel_launch(void* const* d_in, const int* in_sizes, int n_in,
                              void* d_out, int out_size, void* d_ws, size_t ws_size,
                              hipStream_t stream) {
  (void)in_sizes; (void)n_in; (void)out_size; (void)ws_size;
  const float* tokens = (const float*)d_in[0];
  const float* Wqg = (const float*)d_in[1];
  const float* Wkv = (const float*)d_in[2];
  const float* Wo = (const float*)d_in[3];
  const float* ls_iaw = (const float*)d_in[4];
  const float* ls_hws = (const float*)d_in[5];
  float* out = (float*)d_out;
  char* ws = (char*)d_ws;

  // workspace layout (phased aliasing, total 109 MB):
  u16* WoT = (u16*)(ws + 0);                     // 8,388,608 B
  char* regA = ws + 8388608;                     // 50,331,648 B
  u16* tok_bf = (u16*)(regA);                    // phase A-B (16.8MB)
  u16* WqgkvT = (u16*)(regA + 16777216);         // phase A-B (25.2MB) [6144][2048]
  u16* qn = (u16*)(regA);                        // phase C-D
  u16* kn = (u16*)(regA + 8388608);
  u16* vnT = (u16*)(regA + 16777216);
  u16* gact = (u16*)(regA + 33554432);
  char* regB = ws + 58720256;                    // 50,331,648 B
  u16* qgkv_raw = (u16*)(regB);                  // phase B-C [4096][6144]
  u16* pre_out = (u16*)(regB);                   // phase D-E

  k_cvt<<<4096, 256, 0, stream>>>(tokens, tok_bf, 8388608);
  k_cvtT<<<dim3(96, 64), 256, 0, stream>>>(Wqg, WqgkvT, 2048, 3072);
  k_cvtT<<<dim3(96, 64), 256, 0, stream>>>(Wkv, WqgkvT + (size_t)3072 * 2048, 2048, 3072);
  k_cvtT<<<dim3(64, 64), 256, 0, stream>>>(Wo, WoT, 2048, 2048);

  // merged projection: 128x384 tile, grid 512 = 2 exact rounds, 128KB LDS
  k_gemmU<3, 0><<<512, 512, 131072, stream>>>(tok_bf, WqgkvT, qgkv_raw, 6144, 2048);

  k_norm<<<dim3(32, 32), 256, 0, stream>>>(qgkv_raw, qn, kn, vnT, gact);

  k_attn<<<dim3(16, 32), 256, 49152, stream>>>(qn, kn, vnT, gact, ls_iaw, ls_hws, pre_out);

  // final projection: 128x256 tile, grid 256 = 1 exact round, 96KB LDS
  k_gemmU<2, 1><<<256, 512, 98304, stream>>>(pre_out, WoT, out, 2048, 2048);
}

// Round 12
// 261.431 us; speedup vs baseline: 1.1953x; 1.0415x over previous
//
#include <hip/hip_runtime.h>
#include <hip/hip_bf16.h>
#include <stdint.h>

// GatedScreeningTile: B=2 N=2048 DIM=2048 H=16 DK=64 DV=128 DIM_INNER=3072
// Pipeline: cvt/transpose -> k_gemmP2(qg|kv) -> normalize -> fused attn -> k_gemmU<2>(out)
// k_gemmP2: 256x384, BK=32, TRIPLE-buffered LDS (120KB), grid 256 = 1 exact CU round,
// 2 phases/tile, counted vmcnt(5) (stage 2 tiles ahead; never drains to 0 mid-loop).

typedef unsigned short u16;
typedef __bf16 bf16x8 __attribute__((ext_vector_type(8)));
typedef u16 u16x8 __attribute__((ext_vector_type(8)));
typedef float f32x4 __attribute__((ext_vector_type(4)));
typedef float f32x16 __attribute__((ext_vector_type(16)));
typedef int i32x4 __attribute__((ext_vector_type(4)));

#define DEVINL __device__ __forceinline__

DEVINL u16 f2bf(float f) {
  union { float f; uint32_t u; } v; v.f = f;
  uint32_t r = (v.u + 0x7FFFu + ((v.u >> 16) & 1u)) >> 16;
  return (u16)r;
}
DEVINL float bf2f(u16 x) {
  union { uint32_t u; float f; } v; v.u = ((uint32_t)x) << 16;
  return v.f;
}
DEVINL bf16x8 as_bf(u16x8 v) { return __builtin_bit_cast(bf16x8, v); }

typedef const __attribute__((address_space(1))) uint32_t* gptr_t;
typedef __attribute__((address_space(3))) uint32_t* lptr_t;
DEVINL void gload_lds16(const void* g, void* l) {
  __builtin_amdgcn_global_load_lds((gptr_t)g, (lptr_t)l, 16, 0, 0);
}

DEVINL f32x4 mfma16(u16x8 a, u16x8 b, f32x4 c) {
  return __builtin_amdgcn_mfma_f32_16x16x32_bf16(as_bf(a), as_bf(b), c, 0, 0, 0);
}
DEVINL f32x16 mfma32(u16x8 a, u16x8 b, f32x16 c) {
  return __builtin_amdgcn_mfma_f32_32x32x16_bf16(as_bf(a), as_bf(b), c, 0, 0, 0);
}

// ---------------- fp32 -> bf16 convert (same layout) ----------------
__global__ void k_cvt(const float* __restrict__ src, u16* __restrict__ dst, int n) {
  int i = (blockIdx.x * blockDim.x + threadIdx.x) * 4;
  int stride = gridDim.x * blockDim.x * 4;
  for (; i < n; i += stride) {
    float4 f = *(const float4*)(src + i);
    ushort4 o;
    o.x = f2bf(f.x); o.y = f2bf(f.y); o.z = f2bf(f.z); o.w = f2bf(f.w);
    *(ushort4*)(dst + i) = o;
  }
}

// ---------------- fp32 (RxC) -> bf16 transposed (CxR) ----------------
__global__ void k_cvtT(const float* __restrict__ src, u16* __restrict__ dst, int R, int C) {
  __shared__ float tile[32][33];
  int c0 = blockIdx.x * 32, r0 = blockIdx.y * 32;
  int tc = threadIdx.x & 31, tr = threadIdx.x >> 5;  // tr 0..7
#pragma unroll
  for (int i = 0; i < 4; i++) {
    int r = tr + i * 8;
    tile[r][tc] = src[(size_t)(r0 + r) * C + c0 + tc];
  }
  __syncthreads();
#pragma unroll
  for (int i = 0; i < 4; i++) {
    int r = tr + i * 8;  // row in dst tile (= src col)
    dst[(size_t)(c0 + r) * R + r0 + tc] = f2bf(tile[tc][r]);
  }
}

// ---------------- k_gemmP2: merged projection, 256x384, BK=32, triple-buffer ----------------
// 8 waves (2m x 4n); wave tile 128x96 -> acc[2 mh][4 mi][6 nj] (48 frags, 192 VGPR).
// LDS: A [3][256 rows][32k] 16KB/slot + B [3][384][32] 24KB/slot = 120KB.
// Swizzle (64B rows, 4 granules of 16B): LDS[row][g] = global[row][g ^ ((row>>1)&3)];
// frag read g = hi ^ ((fr>>1)&3) -> every consecutive-8-lane group hits 8 distinct
// 16B columns (conflict-free); staging source pre-swizzled, LDS dest linear.
// Schedule per tile t (slot s=t%3): [vmcnt(5) | vmcnt(0) at last]; barrier;
//   p0: read B(6)+A0(4) frags; stage(t+2): A x2 + B0; 24 MFMA (mh=0)
//   barrier; p1: read A1(4); stage(t+2): B1,B2; 24 MFMA (mh=1)
// Ledger: 5 loads/tile, 2 tiles in flight (10 outstanding) -> vmcnt(5) waits exactly
// stage(t) (issued 2 full tiles ago ~1200cyc > 900cyc HBM). Readers of slot (t+2)%3
// = tile t-1; all retired before tile-t top barrier (reg-dep of t-1's MFMAs).
__global__ __launch_bounds__(512, 1) void k_gemmP2(const u16* __restrict__ A,
                                                   const u16* __restrict__ Bt,
                                                   u16* __restrict__ C,
                                                   int Nt, int K) {
  extern __shared__ char smem[];
  u16* As = (u16*)smem;             // [3][256][32] u16, slot stride 8192
  u16* Bs = (u16*)(smem + 49152);   // [3][384][32] u16, slot stride 12288

  const int tid = threadIdx.x, lane = tid & 63, wid = tid >> 6;

  // XCD remap: grid 256 = 16 m-panels x 16 n-panels; xcd = bid&7 owns 2 n-panels.
  const int bid = blockIdx.x;
  const int xcd = bid & 7, idx = bid >> 3;  // idx 0..31
  const int m0 = (idx & 15) * 256;
  const int n0 = (xcd * 2 + (idx >> 4)) * 384;

  const int wm = (wid >> 2) * 128, wn = (wid & 3) * 96;
  const int fr = lane & 15, hi = lane >> 4, frow = hi * 4;
  const int kg = (fr >> 1) & 3;  // frag-read granule key

  f32x4 acc[2][4][6] = {};  // [mh][mi][nj]

  // staging: per instr block covers 128 rows of 64B; wave w rows w*16+(lane>>2);
  // src granule (lane&3) ^ ((lane>>3)&3)  [= (row>>1)&3 key]; LDS dest linear.
  const int sg = ((lane & 3) ^ ((lane >> 3) & 3)) << 3;  // u16
  const int srow = wid * 16 + (lane >> 2);
  const u16* gA0 = A + (size_t)(m0 + srow) * K + sg;
  const u16* gB0 = Bt + (size_t)(n0 + srow) * K + sg;
  const size_t r128 = (size_t)128 * K;
  const int dwave = wid * 512;  // u16, wave-uniform dest base component

#define SA(S, I, KT) gload_lds16(gA0 + (size_t)(I) * r128 + (KT), As + (S) * 8192 + (I) * 4096 + dwave)
#define SB(S, I, KT) gload_lds16(gB0 + (size_t)(I) * r128 + (KT), Bs + (S) * 12288 + (I) * 4096 + dwave)

  // prologue: stage tiles 0 and 1
  SA(0, 0, 0); SA(0, 1, 0); SB(0, 0, 0); SB(0, 1, 0); SB(0, 2, 0);
  SA(1, 0, 32); SA(1, 1, 32); SB(1, 0, 32); SB(1, 1, 32); SB(1, 2, 32);

  const int NTI = K >> 5;  // 64
  int s = 0;
  for (int t = 0; t < NTI; t++) {
    const int s2 = (s + 2 >= 3) ? s - 1 : s + 2;
    const int ktn = (t + 2) << 5;
    const bool do_stage = (t + 2) < NTI;

    // tile top: stage(t) landed (issued 2 tiles ago); stage(t+1) keeps flying
    if (t < NTI - 1) {
      asm volatile("s_waitcnt vmcnt(5)" ::: "memory");
    } else {
      asm volatile("s_waitcnt vmcnt(0)" ::: "memory");
    }
    __builtin_amdgcn_s_barrier();
    asm volatile("" ::: "memory");

    const u16* Ab = As + s * 8192;
    const u16* Bb = Bs + s * 12288;

    // ---- phase 0: mh = 0 ----
    u16x8 bf[6];
#pragma unroll
    for (int nj = 0; nj < 6; nj++)
      bf[nj] = *(const u16x8*)(Bb + (wn + nj * 16 + fr) * 32 + ((hi ^ kg) << 3));
    u16x8 af[4];
#pragma unroll
    for (int mi = 0; mi < 4; mi++)
      af[mi] = *(const u16x8*)(Ab + (wm + mi * 16 + fr) * 32 + ((hi ^ kg) << 3));
    if (do_stage) { SA(s2, 0, ktn); SA(s2, 1, ktn); SB(s2, 0, ktn); }
    __builtin_amdgcn_s_setprio(1);
#pragma unroll
    for (int mi = 0; mi < 4; mi++)
#pragma unroll
      for (int nj = 0; nj < 6; nj++)
        acc[0][mi][nj] = mfma16(af[mi], bf[nj], acc[0][mi][nj]);
    __builtin_amdgcn_s_setprio(0);

    // ---- phase 1: mh = 1 ----
    __builtin_amdgcn_s_barrier();
    asm volatile("" ::: "memory");
#pragma unroll
    for (int mi = 0; mi < 4; mi++)
      af[mi] = *(const u16x8*)(Ab + (wm + 64 + mi * 16 + fr) * 32 + ((hi ^ kg) << 3));
    if (do_stage) { SB(s2, 1, ktn); SB(s2, 2, ktn); }
    __builtin_amdgcn_s_setprio(1);
#pragma unroll
    for (int mi = 0; mi < 4; mi++)
#pragma unroll
      for (int nj = 0; nj < 6; nj++)
        acc[1][mi][nj] = mfma16(af[mi], bf[nj], acc[1][mi][nj]);
    __builtin_amdgcn_s_setprio(0);

    s = (s + 1 >= 3) ? 0 : s + 1;
  }
#undef SA
#undef SB

#pragma unroll
  for (int mh = 0; mh < 2; mh++)
#pragma unroll
    for (int mi = 0; mi < 4; mi++)
#pragma unroll
      for (int nj = 0; nj < 6; nj++)
#pragma unroll
        for (int j = 0; j < 4; j++) {
          const size_t row = m0 + wm + mh * 64 + mi * 16 + frow + j;
          const size_t col = n0 + wn + nj * 16 + fr;
          C[row * Nt + col] = f2bf(acc[mh][mi][nj][j]);
        }
}

// ---------------- k_gemmU: final projection (grid 256, double-buffer, 1 barrier/tile) ----------------
template <int NI, int F32OUT>
__global__ __launch_bounds__(512, 1) void k_gemmU(const u16* __restrict__ A,
                                                  const u16* __restrict__ Bt,
                                                  void* __restrict__ Cout,
                                                  int Nt, int K) {
  constexpr int BN = NI * 128;
  constexpr int NLB = BN / 64;
  constexpr int ABUF = 128 * 64;
  constexpr int BBUF = BN * 64;
  extern __shared__ char smem[];
  u16* As = (u16*)smem;
  u16* Bs = (u16*)(smem + 2 * ABUF * 2);

  const int tid = threadIdx.x, lane = tid & 63, wid = tid >> 6;

  const int NPN = Nt / BN;
  const int bid = blockIdx.x;
  const int xcd = bid & 7, idx = bid >> 3;
  const int npx = NPN >> 3;
  const int m0 = (idx & 31) * 128;
  const int n0 = (xcd * npx + (idx >> 5)) * BN;

  const int mq = (wid >> 2) * 32, nq = (wid & 3) * (BN / 8);
  const int fr = lane & 15, hi = lane >> 4, frow = hi * 4, rb7 = fr & 7;

  f32x4 acc[2][2][2][NI] = {};

  const int schunk = ((lane & 7) ^ ((lane >> 3) & 7)) << 3;
  const int srow = wid * 8 + (lane >> 3);
  const u16* ga0 = A + (size_t)(m0 + srow) * K + schunk;
  const u16* gb0 = Bt + (size_t)(n0 + srow) * K + schunk;
  const size_t l64 = (size_t)64 * K;
  const int dwave = wid * 512;

#define STG(T, P)                                                                     \
  {                                                                                   \
    const int kt_ = (T) << 6;                                                         \
    _Pragma("unroll") for (int i = 0; i < 2; i++)                                     \
        gload_lds16(ga0 + (size_t)i * l64 + kt_, As + (P) * ABUF + i * 4096 + dwave); \
    _Pragma("unroll") for (int i = 0; i < NLB; i++)                                   \
        gload_lds16(gb0 + (size_t)i * l64 + kt_, Bs + (P) * BBUF + i * 4096 + dwave); \
  }

  STG(0, 0);

  const int NTI = K >> 6;
  for (int t = 0; t < NTI; t++) {
    asm volatile("s_waitcnt vmcnt(0) lgkmcnt(0)" ::: "memory");
    __builtin_amdgcn_s_barrier();
    asm volatile("" ::: "memory");

    const int p = t & 1;
    if (t + 1 < NTI) STG(t + 1, p ^ 1);

    const u16* Ab = As + p * ABUF;
    const u16* Bb = Bs + p * BBUF;

    u16x8 af[2][2][2], bf[2][NI][2];
#pragma unroll
    for (int MH = 0; MH < 2; MH++)
#pragma unroll
      for (int mi = 0; mi < 2; mi++)
#pragma unroll
        for (int kk = 0; kk < 2; kk++) {
          const int row = MH * 64 + mq + mi * 16 + fr;
          af[MH][mi][kk] = *(const u16x8*)(Ab + row * 64 + (((kk * 4 + hi) ^ rb7) << 3));
        }
#pragma unroll
    for (int NH = 0; NH < 2; NH++)
#pragma unroll
      for (int ni = 0; ni < NI; ni++)
#pragma unroll
        for (int kk = 0; kk < 2; kk++) {
          const int row = NH * (BN / 2) + nq + ni * 16 + fr;
          bf[NH][ni][kk] = *(const u16x8*)(Bb + row * 64 + (((kk * 4 + hi) ^ rb7) << 3));
        }

    __builtin_amdgcn_s_setprio(1);
#pragma unroll
    for (int kk = 0; kk < 2; kk++)
#pragma unroll
      for (int MH = 0; MH < 2; MH++)
#pragma unroll
        for (int mi = 0; mi < 2; mi++)
#pragma unroll
          for (int NH = 0; NH < 2; NH++)
#pragma unroll
            for (int ni = 0; ni < NI; ni++)
              acc[MH][mi][NH][ni] = mfma16(af[MH][mi][kk], bf[NH][ni][kk], acc[MH][mi][NH][ni]);
    __builtin_amdgcn_s_setprio(0);
  }
#undef STG

#pragma unroll
  for (int MH = 0; MH < 2; MH++)
#pragma unroll
    for (int mi = 0; mi < 2; mi++)
#pragma unroll
      for (int NH = 0; NH < 2; NH++)
#pragma unroll
        for (int ni = 0; ni < NI; ni++)
#pragma unroll
          for (int j = 0; j < 4; j++) {
            const size_t row = m0 + MH * 64 + mq + mi * 16 + frow + j;
            const size_t col = n0 + NH * (BN / 2) + nq + ni * 16 + fr;
            if (F32OUT) ((float*)Cout)[row * Nt + col] = acc[MH][mi][NH][ni][j];
            else ((u16*)Cout)[row * Nt + col] = f2bf(acc[MH][mi][NH][ni][j]);
          }
}

// ---------------- normalize: qgkv raw -> qn, kn, vnT, gact ----------------
__global__ __launch_bounds__(256, 4) void k_norm(const u16* __restrict__ qgkv,
                                                 u16* __restrict__ qn, u16* __restrict__ kn,
                                                 u16* __restrict__ vnT, u16* __restrict__ gact) {
  __shared__ u16 vt[128 * 64];  // [d][nl], col swizzle: c' = nl ^ ((d&15)<<2)
  const int tid = threadIdx.x, lane = tid & 63, wid = tid >> 6;
  const int hb = blockIdx.y;            // b*16 + h
  const int h = hb & 15, b = hb >> 4;
  const int n0 = blockIdx.x * 64;

  for (int s = 0; s < 16; s++) {
    const int nl = wid * 16 + s;        // 0..63
    const int n = n0 + nl;
    const size_t bn = (size_t)b * 2048 + n;
    const size_t baseq = bn * 6144 + (size_t)h * 192;
    const size_t basek = baseq + 3072;

    float q = bf2f(qgkv[baseq + lane]);
    float g0 = bf2f(qgkv[baseq + 64 + lane]);
    float g1 = bf2f(qgkv[baseq + 128 + lane]);
    float k = bf2f(qgkv[basek + lane]);
    float v0 = bf2f(qgkv[basek + 64 + lane]);
    float v1 = bf2f(qgkv[basek + 128 + lane]);

    float qs = q * q, ks = k * k, vs = v0 * v0 + v1 * v1;
#pragma unroll
    for (int m = 1; m < 64; m <<= 1) {
      qs += __shfl_xor(qs, m);
      ks += __shfl_xor(ks, m);
      vs += __shfl_xor(vs, m);
    }
    float rq = 1.f / fmaxf(sqrtf(qs), 1e-12f);
    float rk = 1.f / fmaxf(sqrtf(ks), 1e-12f);
    float rv = 1.f / fmaxf(sqrtf(vs), 1e-12f);

    qn[((size_t)hb * 2048 + n) * 64 + lane] = f2bf(q * rq);
    kn[((size_t)hb * 2048 + n) * 64 + lane] = f2bf(k * rk);
    float s0 = g0 / (1.f + __expf(-g0));
    float s1 = g1 / (1.f + __expf(-g1));
    gact[((size_t)hb * 2048 + n) * 128 + lane] = f2bf(tanhf(s0));
    gact[((size_t)hb * 2048 + n) * 128 + 64 + lane] = f2bf(tanhf(s1));

    const int d0 = lane, d1 = 64 + lane;
    vt[d0 * 64 + (nl ^ ((d0 & 15) << 2))] = f2bf(v0 * rv);
    vt[d1 * 64 + (nl ^ ((d1 & 15) << 2))] = f2bf(v1 * rv);
  }
  __syncthreads();

  // write-out: sigma(col) = swap bits 2<->3 within n&31 (preserves bits 0-1)
#pragma unroll
  for (int p = 0; p < 8; p++) {
    const int d = p * 16 + (tid >> 4);
    const int nq = (tid & 15) * 4;
    const int cb = nq ^ ((d & 15) << 2);
    const int nq2 = (nq & ~12) | ((nq & 4) << 1) | ((nq & 8) >> 1);
    ushort4 o;
    o.x = vt[d * 64 + cb + 0];
    o.y = vt[d * 64 + cb + 1];
    o.z = vt[d * 64 + cb + 2];
    o.w = vt[d * 64 + cb + 3];
    *(ushort4*)(vnT + ((size_t)hb * 128 + d) * 2048 + n0 + nq2) = o;
  }
}

// ---------------- fused screened attention (swapped-operand 32x32, P in registers) ----------------
__global__ __launch_bounds__(256, 2) void k_attn(const u16* __restrict__ qn,
                                                 const u16* __restrict__ kn,
                                                 const u16* __restrict__ vnT,
                                                 const u16* __restrict__ gact,
                                                 const float* __restrict__ ls_iaw,
                                                 const float* __restrict__ ls_hws,
                                                 u16* __restrict__ pre_out) {
  extern __shared__ char smem[];
  u16* KsB = (u16*)smem;                 // [2][64 k][64 dk]  8KB each
  u16* VsB = (u16*)(smem + 16384);       // [2][128 d][64 k'] 16KB each (k' sigma-order)
  u16* Os = (u16*)smem;                  // epilogue reuse: [128 q][132 d] 33.8KB

  const int tid = threadIdx.x, lane = tid & 63, wid = tid >> 6;
  const int bid = blockIdx.y * 16 + blockIdx.x;
  const int bh = (bid & 7) * 4 + ((bid >> 3) & 3);
  const int n0 = (bid >> 5) * 128;
  const int h = bh & 15;
  const int l31 = lane & 31, L = lane >> 5, rb = l31 & 7;
  const float r = 1.f / (__expf(ls_iaw[h]) + 1.f);
  const float c1 = 1.f - r;
  const float whs = __expf(ls_hws[h]);

  const int wq = wid * 32;
  const u16* qrow = qn + ((size_t)bh * 2048 + n0 + wq + l31) * 64;
  u16x8 qf[4];
#pragma unroll
  for (int c = 0; c < 4; c++) qf[c] = *(const u16x8*)(qrow + c * 16 + L * 8);

  f32x16 acc[4] = {};  // acc[dt]: D[d = dt*32 + (reg&3)+8*(reg>>2)+4L][q = l31]
  const u16* kbase = kn + (size_t)bh * 2048 * 64;
  const u16* vbase = vnT + (size_t)bh * 128 * 2048;

  int ks_goff[2];
#pragma unroll
  for (int i = 0; i < 2; i++) {
    int row = wid * 16 + i * 8 + (lane >> 3);
    ks_goff[i] = row * 64 + (((lane & 7) ^ (row & 7)) << 3);
  }
  int vs_goff[4];
#pragma unroll
  for (int i = 0; i < 4; i++) {
    int row = wid * 32 + i * 8 + (lane >> 3);
    vs_goff[i] = row * 2048 + (((lane & 7) ^ (row & 7)) << 3);
  }

  {
    u16* KsC = KsB + wid * 1024;
    u16* VsC = VsB + wid * 2048;
#pragma unroll
    for (int i = 0; i < 2; i++) gload_lds16(kbase + ks_goff[i], KsC + i * 512);
#pragma unroll
    for (int i = 0; i < 4; i++) gload_lds16(vbase + vs_goff[i], VsC + i * 512);
  }

  int cur = 0;
  for (int t = 0; t < 32; t++) {
    asm volatile("s_waitcnt vmcnt(0) lgkmcnt(0)" ::: "memory");
    __builtin_amdgcn_s_barrier();
    asm volatile("" ::: "memory");

    if (t < 31) {
      const int kv0 = (t + 1) * 64;
      u16* KsC2 = KsB + (cur ^ 1) * 4096 + wid * 1024;
      u16* VsC2 = VsB + (cur ^ 1) * 8192 + wid * 2048;
#pragma unroll
      for (int i = 0; i < 2; i++) gload_lds16(kbase + (size_t)kv0 * 64 + ks_goff[i], KsC2 + i * 512);
#pragma unroll
      for (int i = 0; i < 4; i++) gload_lds16(vbase + (size_t)vs_goff[i] + kv0, VsC2 + i * 512);
    }

    const u16* KsC = KsB + cur * 4096;
    const u16* VsC = VsB + cur * 8192;

    f32x16 sT0 = {}, sT1 = {};
    __builtin_amdgcn_s_setprio(1);
#pragma unroll
    for (int c = 0; c < 4; c++) {
      u16x8 kf0 = *(const u16x8*)(KsC + (0 + l31) * 64 + (((2 * c + L) ^ rb) << 3));
      u16x8 kf1 = *(const u16x8*)(KsC + (32 + l31) * 64 + (((2 * c + L) ^ rb) << 3));
      sT0 = mfma32(kf0, qf[c], sT0);
      sT1 = mfma32(kf1, qf[c], sT1);
    }
    __builtin_amdgcn_s_setprio(0);

    uint32_t w[2][4][2];
#pragma unroll
    for (int m = 0; m < 4; m++)
#pragma unroll
      for (int p = 0; p < 2; p++) {
        float a0 = fmaxf(0.f, fmaf(r, sT0[4 * m + 2 * p], c1));
        float a1 = fmaxf(0.f, fmaf(r, sT0[4 * m + 2 * p + 1], c1));
        float b0 = fmaxf(0.f, fmaf(r, sT1[4 * m + 2 * p], c1));
        float b1 = fmaxf(0.f, fmaf(r, sT1[4 * m + 2 * p + 1], c1));
        w[0][m][p] = (uint32_t)f2bf(a0 * a0) | ((uint32_t)f2bf(a1 * a1) << 16);
        w[1][m][p] = (uint32_t)f2bf(b0 * b0) | ((uint32_t)f2bf(b1 * b1) << 16);
      }

    __builtin_amdgcn_s_setprio(1);
#pragma unroll
    for (int kt = 0; kt < 2; kt++)
#pragma unroll
      for (int pair = 0; pair < 2; pair++) {
        i32x4 pw;
        pw[0] = (int)w[kt][2 * pair][0];
        pw[1] = (int)w[kt][2 * pair][1];
        pw[2] = (int)w[kt][2 * pair + 1][0];
        pw[3] = (int)w[kt][2 * pair + 1][1];
        u16x8 pf = __builtin_bit_cast(u16x8, pw);
        const int chunk = 4 * kt + 2 * pair + L;
#pragma unroll
        for (int dt = 0; dt < 4; dt++) {
          u16x8 vf = *(const u16x8*)(VsC + (dt * 32 + l31) * 64 + ((chunk ^ rb) << 3));
          acc[dt] = mfma32(vf, pf, acc[dt]);
        }
      }
    __builtin_amdgcn_s_setprio(0);
    cur ^= 1;
  }

  float ss = 0.f;
#pragma unroll
  for (int dt = 0; dt < 4; dt++)
#pragma unroll
    for (int e = 0; e < 16; e++) { float x = acc[dt][e]; ss += x * x; }
  ss += __shfl_xor(ss, 32);
  float nn = sqrtf(ss);
  float scale = tanhf(nn) / fmaxf(nn, 1e-12f) * whs;

  __syncthreads();

  const int q = wq + l31;
  const size_t grow = ((size_t)bh * 2048 + n0 + q) * 128;
#pragma unroll
  for (int dt = 0; dt < 4; dt++)
#pragma unroll
    for (int m = 0; m < 4; m++) {
      const int d = dt * 32 + 8 * m + 4 * L;
      ushort4 gv = *(const ushort4*)(gact + grow + d);
      ushort4 o;
      o.x = f2bf(acc[dt][4 * m + 0] * scale * bf2f(gv.x));
      o.y = f2bf(acc[dt][4 * m + 1] * scale * bf2f(gv.y));
      o.z = f2bf(acc[dt][4 * m + 2] * scale * bf2f(gv.z));
      o.w = f2bf(acc[dt][4 * m + 3] * scale * bf2f(gv.w));
      *(ushort4*)(Os + q * 132 + d) = o;
    }
  __syncthreads();

  const int orow = tid >> 1, oc0 = (tid & 1) * 64;
  const size_t obase = ((size_t)(bh >> 4) * 2048 + n0 + orow) * 2048 + (size_t)h * 128 + oc0;
#pragma unroll
  for (int j = 0; j < 16; j++) {
    ushort4 v = *(const ushort4*)(Os + orow * 132 + oc0 + 4 * j);
    *(ushort4*)(pre_out + obase + 4 * j) = v;
  }
}

extern "C" void kernel_launch(void* const* d_in, const int* in_sizes, int n_in,
                              void* d_out, int out_size, void* d_ws, size_t ws_size,
                              hipStream_t stream) {
  (void)in_sizes; (void)n_in; (void)out_size; (void)ws_size;
  const float* tokens = (const float*)d_in[0];
  const float* Wqg = (const float*)d_in[1];
  const float* Wkv = (const float*)d_in[2];
  const float* Wo = (const float*)d_in[3];
  const float* ls_iaw = (const float*)d_in[4];
  const float* ls_hws = (const float*)d_in[5];
  float* out = (float*)d_out;
  char* ws = (char*)d_ws;

  // workspace layout (phased aliasing, total 109 MB):
  u16* WoT = (u16*)(ws + 0);                     // 8,388,608 B
  char* regA = ws + 8388608;                     // 50,331,648 B
  u16* tok_bf = (u16*)(regA);                    // phase A-B (16.8MB)
  u16* WqgkvT = (u16*)(regA + 16777216);         // phase A-B (25.2MB) [6144][2048]
  u16* qn = (u16*)(regA);                        // phase C-D
  u16* kn = (u16*)(regA + 8388608);
  u16* vnT = (u16*)(regA + 16777216);
  u16* gact = (u16*)(regA + 33554432);
  char* regB = ws + 58720256;                    // 50,331,648 B
  u16* qgkv_raw = (u16*)(regB);                  // phase B-C [4096][6144]
  u16* pre_out = (u16*)(regB);                   // phase D-E

  k_cvt<<<4096, 256, 0, stream>>>(tokens, tok_bf, 8388608);
  k_cvtT<<<dim3(96, 64), 256, 0, stream>>>(Wqg, WqgkvT, 2048, 3072);
  k_cvtT<<<dim3(96, 64), 256, 0, stream>>>(Wkv, WqgkvT + (size_t)3072 * 2048, 2048, 3072);
  k_cvtT<<<dim3(64, 64), 256, 0, stream>>>(Wo, WoT, 2048, 2048);

  // merged projection: 256x384 tile, grid 256 = 1 exact round, 120KB LDS triple-buffer
  k_gemmP2<<<256, 512, 122880, stream>>>(tok_bf, WqgkvT, qgkv_raw, 6144, 2048);

  k_norm<<<dim3(32, 32), 256, 0, stream>>>(qgkv_raw, qn, kn, vnT, gact);

  k_attn<<<dim3(16, 32), 256, 49152, stream>>>(qn, kn, vnT, gact, ls_iaw, ls_hws, pre_out);

  // final projection: 128x256 tile, grid 256 = 1 exact round, 96KB LDS
  k_gemmU<2, 1><<<256, 512, 98304, stream>>>(pre_out, WoT, out, 2048, 2048);
}

// Round 13
// 260.782 us; speedup vs baseline: 1.1983x; 1.0025x over previous
//
#include <hip/hip_runtime.h>
#include <hip/hip_bf16.h>
#include <stdint.h>

// GatedScreeningTile: B=2 N=2048 DIM=2048 H=16 DK=64 DV=128 DIM_INNER=3072
// Pipeline: cvt/transpose -> k_gemmP2(qg|kv) -> normalize -> fused attn -> k_gemmU<2>(out)
// R13: counted-vmcnt 3-slot pipeline (R12's verified gemmP2 schedule) propagated to
// k_attn (vmcnt(6), 72KB LDS, 2 blocks/CU) and k_gemmU (vmcnt(6), 144KB LDS).

typedef unsigned short u16;
typedef __bf16 bf16x8 __attribute__((ext_vector_type(8)));
typedef u16 u16x8 __attribute__((ext_vector_type(8)));
typedef float f32x4 __attribute__((ext_vector_type(4)));
typedef float f32x16 __attribute__((ext_vector_type(16)));
typedef int i32x4 __attribute__((ext_vector_type(4)));

#define DEVINL __device__ __forceinline__

DEVINL u16 f2bf(float f) {
  union { float f; uint32_t u; } v; v.f = f;
  uint32_t r = (v.u + 0x7FFFu + ((v.u >> 16) & 1u)) >> 16;
  return (u16)r;
}
DEVINL float bf2f(u16 x) {
  union { uint32_t u; float f; } v; v.u = ((uint32_t)x) << 16;
  return v.f;
}
DEVINL bf16x8 as_bf(u16x8 v) { return __builtin_bit_cast(bf16x8, v); }

typedef const __attribute__((address_space(1))) uint32_t* gptr_t;
typedef __attribute__((address_space(3))) uint32_t* lptr_t;
DEVINL void gload_lds16(const void* g, void* l) {
  __builtin_amdgcn_global_load_lds((gptr_t)g, (lptr_t)l, 16, 0, 0);
}

DEVINL f32x4 mfma16(u16x8 a, u16x8 b, f32x4 c) {
  return __builtin_amdgcn_mfma_f32_16x16x32_bf16(as_bf(a), as_bf(b), c, 0, 0, 0);
}
DEVINL f32x16 mfma32(u16x8 a, u16x8 b, f32x16 c) {
  return __builtin_amdgcn_mfma_f32_32x32x16_bf16(as_bf(a), as_bf(b), c, 0, 0, 0);
}

// ---------------- fp32 -> bf16 convert (same layout) ----------------
__global__ void k_cvt(const float* __restrict__ src, u16* __restrict__ dst, int n) {
  int i = (blockIdx.x * blockDim.x + threadIdx.x) * 4;
  int stride = gridDim.x * blockDim.x * 4;
  for (; i < n; i += stride) {
    float4 f = *(const float4*)(src + i);
    ushort4 o;
    o.x = f2bf(f.x); o.y = f2bf(f.y); o.z = f2bf(f.z); o.w = f2bf(f.w);
    *(ushort4*)(dst + i) = o;
  }
}

// ---------------- fp32 (RxC) -> bf16 transposed (CxR) ----------------
__global__ void k_cvtT(const float* __restrict__ src, u16* __restrict__ dst, int R, int C) {
  __shared__ float tile[32][33];
  int c0 = blockIdx.x * 32, r0 = blockIdx.y * 32;
  int tc = threadIdx.x & 31, tr = threadIdx.x >> 5;  // tr 0..7
#pragma unroll
  for (int i = 0; i < 4; i++) {
    int r = tr + i * 8;
    tile[r][tc] = src[(size_t)(r0 + r) * C + c0 + tc];
  }
  __syncthreads();
#pragma unroll
  for (int i = 0; i < 4; i++) {
    int r = tr + i * 8;  // row in dst tile (= src col)
    dst[(size_t)(c0 + r) * R + r0 + tc] = f2bf(tile[tc][r]);
  }
}

// ---------------- k_gemmP2: merged projection, 256x384, BK=32, triple-buffer ----------------
// (R12-verified: 2 phases/tile, counted vmcnt(5), stage 2 tiles ahead, 120KB LDS.)
__global__ __launch_bounds__(512, 1) void k_gemmP2(const u16* __restrict__ A,
                                                   const u16* __restrict__ Bt,
                                                   u16* __restrict__ C,
                                                   int Nt, int K) {
  extern __shared__ char smem[];
  u16* As = (u16*)smem;             // [3][256][32] u16, slot stride 8192
  u16* Bs = (u16*)(smem + 49152);   // [3][384][32] u16, slot stride 12288

  const int tid = threadIdx.x, lane = tid & 63, wid = tid >> 6;

  const int bid = blockIdx.x;
  const int xcd = bid & 7, idx = bid >> 3;  // idx 0..31
  const int m0 = (idx & 15) * 256;
  const int n0 = (xcd * 2 + (idx >> 4)) * 384;

  const int wm = (wid >> 2) * 128, wn = (wid & 3) * 96;
  const int fr = lane & 15, hi = lane >> 4, frow = hi * 4;
  const int kg = (fr >> 1) & 3;

  f32x4 acc[2][4][6] = {};

  const int sg = ((lane & 3) ^ ((lane >> 3) & 3)) << 3;
  const int srow = wid * 16 + (lane >> 2);
  const u16* gA0 = A + (size_t)(m0 + srow) * K + sg;
  const u16* gB0 = Bt + (size_t)(n0 + srow) * K + sg;
  const size_t r128 = (size_t)128 * K;
  const int dwave = wid * 512;

#define SA(S, I, KT) gload_lds16(gA0 + (size_t)(I) * r128 + (KT), As + (S) * 8192 + (I) * 4096 + dwave)
#define SB(S, I, KT) gload_lds16(gB0 + (size_t)(I) * r128 + (KT), Bs + (S) * 12288 + (I) * 4096 + dwave)

  SA(0, 0, 0); SA(0, 1, 0); SB(0, 0, 0); SB(0, 1, 0); SB(0, 2, 0);
  SA(1, 0, 32); SA(1, 1, 32); SB(1, 0, 32); SB(1, 1, 32); SB(1, 2, 32);

  const int NTI = K >> 5;  // 64
  int s = 0;
  for (int t = 0; t < NTI; t++) {
    const int s2 = (s + 2 >= 3) ? s - 1 : s + 2;
    const int ktn = (t + 2) << 5;
    const bool do_stage = (t + 2) < NTI;

    if (t < NTI - 1) {
      asm volatile("s_waitcnt vmcnt(5)" ::: "memory");
    } else {
      asm volatile("s_waitcnt vmcnt(0)" ::: "memory");
    }
    __builtin_amdgcn_s_barrier();
    asm volatile("" ::: "memory");

    const u16* Ab = As + s * 8192;
    const u16* Bb = Bs + s * 12288;

    u16x8 bf[6];
#pragma unroll
    for (int nj = 0; nj < 6; nj++)
      bf[nj] = *(const u16x8*)(Bb + (wn + nj * 16 + fr) * 32 + ((hi ^ kg) << 3));
    u16x8 af[4];
#pragma unroll
    for (int mi = 0; mi < 4; mi++)
      af[mi] = *(const u16x8*)(Ab + (wm + mi * 16 + fr) * 32 + ((hi ^ kg) << 3));
    if (do_stage) { SA(s2, 0, ktn); SA(s2, 1, ktn); SB(s2, 0, ktn); }
    __builtin_amdgcn_s_setprio(1);
#pragma unroll
    for (int mi = 0; mi < 4; mi++)
#pragma unroll
      for (int nj = 0; nj < 6; nj++)
        acc[0][mi][nj] = mfma16(af[mi], bf[nj], acc[0][mi][nj]);
    __builtin_amdgcn_s_setprio(0);

    __builtin_amdgcn_s_barrier();
    asm volatile("" ::: "memory");
#pragma unroll
    for (int mi = 0; mi < 4; mi++)
      af[mi] = *(const u16x8*)(Ab + (wm + 64 + mi * 16 + fr) * 32 + ((hi ^ kg) << 3));
    if (do_stage) { SB(s2, 1, ktn); SB(s2, 2, ktn); }
    __builtin_amdgcn_s_setprio(1);
#pragma unroll
    for (int mi = 0; mi < 4; mi++)
#pragma unroll
      for (int nj = 0; nj < 6; nj++)
        acc[1][mi][nj] = mfma16(af[mi], bf[nj], acc[1][mi][nj]);
    __builtin_amdgcn_s_setprio(0);

    s = (s + 1 >= 3) ? 0 : s + 1;
  }
#undef SA
#undef SB

#pragma unroll
  for (int mh = 0; mh < 2; mh++)
#pragma unroll
    for (int mi = 0; mi < 4; mi++)
#pragma unroll
      for (int nj = 0; nj < 6; nj++)
#pragma unroll
        for (int j = 0; j < 4; j++) {
          const size_t row = m0 + wm + mh * 64 + mi * 16 + frow + j;
          const size_t col = n0 + wn + nj * 16 + fr;
          C[row * Nt + col] = f2bf(acc[mh][mi][nj][j]);
        }
}

// ---------------- k_gemmU: final projection (grid 256, TRIPLE-buffer, counted vmcnt) ----------------
// R13: 3 slots (144KB LDS), stage 2 tiles ahead, tile-top vmcnt(6) lgkmcnt(0)
// (6 loads/stage, 12 outstanding -> waits exactly stage(t)); vmcnt(0) at last tile.
template <int NI, int F32OUT>
__global__ __launch_bounds__(512, 1) void k_gemmU(const u16* __restrict__ A,
                                                  const u16* __restrict__ Bt,
                                                  void* __restrict__ Cout,
                                                  int Nt, int K) {
  constexpr int BN = NI * 128;
  constexpr int NLB = BN / 64;
  constexpr int ABUF = 128 * 64;
  constexpr int BBUF = BN * 64;
  extern __shared__ char smem[];
  u16* As = (u16*)smem;                   // [3][128][64]
  u16* Bs = (u16*)(smem + 3 * ABUF * 2);  // [3][BN][64]

  const int tid = threadIdx.x, lane = tid & 63, wid = tid >> 6;

  const int NPN = Nt / BN;
  const int bid = blockIdx.x;
  const int xcd = bid & 7, idx = bid >> 3;
  const int npx = NPN >> 3;
  const int m0 = (idx & 31) * 128;
  const int n0 = (xcd * npx + (idx >> 5)) * BN;

  const int mq = (wid >> 2) * 32, nq = (wid & 3) * (BN / 8);
  const int fr = lane & 15, hi = lane >> 4, frow = hi * 4, rb7 = fr & 7;

  f32x4 acc[2][2][2][NI] = {};

  const int schunk = ((lane & 7) ^ ((lane >> 3) & 7)) << 3;
  const int srow = wid * 8 + (lane >> 3);
  const u16* ga0 = A + (size_t)(m0 + srow) * K + schunk;
  const u16* gb0 = Bt + (size_t)(n0 + srow) * K + schunk;
  const size_t l64 = (size_t)64 * K;
  const int dwave = wid * 512;

#define STG(T, S)                                                                     \
  {                                                                                   \
    const int kt_ = (T) << 6;                                                         \
    _Pragma("unroll") for (int i = 0; i < 2; i++)                                     \
        gload_lds16(ga0 + (size_t)i * l64 + kt_, As + (S) * ABUF + i * 4096 + dwave); \
    _Pragma("unroll") for (int i = 0; i < NLB; i++)                                   \
        gload_lds16(gb0 + (size_t)i * l64 + kt_, Bs + (S) * BBUF + i * 4096 + dwave); \
  }

  STG(0, 0);
  STG(1, 1);

  const int NTI = K >> 6;
  int s = 0;
  for (int t = 0; t < NTI; t++) {
    if (t < NTI - 1) {
      if constexpr (NI == 2) asm volatile("s_waitcnt vmcnt(6) lgkmcnt(0)" ::: "memory");
      else asm volatile("s_waitcnt vmcnt(8) lgkmcnt(0)" ::: "memory");
    } else {
      asm volatile("s_waitcnt vmcnt(0) lgkmcnt(0)" ::: "memory");
    }
    __builtin_amdgcn_s_barrier();
    asm volatile("" ::: "memory");

    if (t + 2 < NTI) {
      const int s2 = (s + 2 >= 3) ? s - 1 : s + 2;
      STG(t + 2, s2);
    }

    const u16* Ab = As + s * ABUF;
    const u16* Bb = Bs + s * BBUF;

    u16x8 af[2][2][2], bf[2][NI][2];
#pragma unroll
    for (int MH = 0; MH < 2; MH++)
#pragma unroll
      for (int mi = 0; mi < 2; mi++)
#pragma unroll
        for (int kk = 0; kk < 2; kk++) {
          const int row = MH * 64 + mq + mi * 16 + fr;
          af[MH][mi][kk] = *(const u16x8*)(Ab + row * 64 + (((kk * 4 + hi) ^ rb7) << 3));
        }
#pragma unroll
    for (int NH = 0; NH < 2; NH++)
#pragma unroll
      for (int ni = 0; ni < NI; ni++)
#pragma unroll
        for (int kk = 0; kk < 2; kk++) {
          const int row = NH * (BN / 2) + nq + ni * 16 + fr;
          bf[NH][ni][kk] = *(const u16x8*)(Bb + row * 64 + (((kk * 4 + hi) ^ rb7) << 3));
        }

    __builtin_amdgcn_s_setprio(1);
#pragma unroll
    for (int kk = 0; kk < 2; kk++)
#pragma unroll
      for (int MH = 0; MH < 2; MH++)
#pragma unroll
        for (int mi = 0; mi < 2; mi++)
#pragma unroll
          for (int NH = 0; NH < 2; NH++)
#pragma unroll
            for (int ni = 0; ni < NI; ni++)
              acc[MH][mi][NH][ni] = mfma16(af[MH][mi][kk], bf[NH][ni][kk], acc[MH][mi][NH][ni]);
    __builtin_amdgcn_s_setprio(0);

    s = (s + 1 >= 3) ? 0 : s + 1;
  }
#undef STG

#pragma unroll
  for (int MH = 0; MH < 2; MH++)
#pragma unroll
    for (int mi = 0; mi < 2; mi++)
#pragma unroll
      for (int NH = 0; NH < 2; NH++)
#pragma unroll
        for (int ni = 0; ni < NI; ni++)
#pragma unroll
          for (int j = 0; j < 4; j++) {
            const size_t row = m0 + MH * 64 + mq + mi * 16 + frow + j;
            const size_t col = n0 + NH * (BN / 2) + nq + ni * 16 + fr;
            if (F32OUT) ((float*)Cout)[row * Nt + col] = acc[MH][mi][NH][ni][j];
            else ((u16*)Cout)[row * Nt + col] = f2bf(acc[MH][mi][NH][ni][j]);
          }
}

// ---------------- normalize: qgkv raw -> qn, kn, vnT, gact ----------------
__global__ __launch_bounds__(256, 4) void k_norm(const u16* __restrict__ qgkv,
                                                 u16* __restrict__ qn, u16* __restrict__ kn,
                                                 u16* __restrict__ vnT, u16* __restrict__ gact) {
  __shared__ u16 vt[128 * 64];  // [d][nl], col swizzle: c' = nl ^ ((d&15)<<2)
  const int tid = threadIdx.x, lane = tid & 63, wid = tid >> 6;
  const int hb = blockIdx.y;            // b*16 + h
  const int h = hb & 15, b = hb >> 4;
  const int n0 = blockIdx.x * 64;

  for (int s = 0; s < 16; s++) {
    const int nl = wid * 16 + s;        // 0..63
    const int n = n0 + nl;
    const size_t bn = (size_t)b * 2048 + n;
    const size_t baseq = bn * 6144 + (size_t)h * 192;
    const size_t basek = baseq + 3072;

    float q = bf2f(qgkv[baseq + lane]);
    float g0 = bf2f(qgkv[baseq + 64 + lane]);
    float g1 = bf2f(qgkv[baseq + 128 + lane]);
    float k = bf2f(qgkv[basek + lane]);
    float v0 = bf2f(qgkv[basek + 64 + lane]);
    float v1 = bf2f(qgkv[basek + 128 + lane]);

    float qs = q * q, ks = k * k, vs = v0 * v0 + v1 * v1;
#pragma unroll
    for (int m = 1; m < 64; m <<= 1) {
      qs += __shfl_xor(qs, m);
      ks += __shfl_xor(ks, m);
      vs += __shfl_xor(vs, m);
    }
    float rq = 1.f / fmaxf(sqrtf(qs), 1e-12f);
    float rk = 1.f / fmaxf(sqrtf(ks), 1e-12f);
    float rv = 1.f / fmaxf(sqrtf(vs), 1e-12f);

    qn[((size_t)hb * 2048 + n) * 64 + lane] = f2bf(q * rq);
    kn[((size_t)hb * 2048 + n) * 64 + lane] = f2bf(k * rk);
    float s0 = g0 / (1.f + __expf(-g0));
    float s1 = g1 / (1.f + __expf(-g1));
    gact[((size_t)hb * 2048 + n) * 128 + lane] = f2bf(tanhf(s0));
    gact[((size_t)hb * 2048 + n) * 128 + 64 + lane] = f2bf(tanhf(s1));

    const int d0 = lane, d1 = 64 + lane;
    vt[d0 * 64 + (nl ^ ((d0 & 15) << 2))] = f2bf(v0 * rv);
    vt[d1 * 64 + (nl ^ ((d1 & 15) << 2))] = f2bf(v1 * rv);
  }
  __syncthreads();

  // write-out: sigma(col) = swap bits 2<->3 within n&31 (preserves bits 0-1)
#pragma unroll
  for (int p = 0; p < 8; p++) {
    const int d = p * 16 + (tid >> 4);
    const int nq = (tid & 15) * 4;
    const int cb = nq ^ ((d & 15) << 2);
    const int nq2 = (nq & ~12) | ((nq & 4) << 1) | ((nq & 8) >> 1);
    ushort4 o;
    o.x = vt[d * 64 + cb + 0];
    o.y = vt[d * 64 + cb + 1];
    o.z = vt[d * 64 + cb + 2];
    o.w = vt[d * 64 + cb + 3];
    *(ushort4*)(vnT + ((size_t)hb * 128 + d) * 2048 + n0 + nq2) = o;
  }
}

// ---------------- fused screened attention (swapped-operand 32x32, P in registers) ----------------
// R13: K/V TRIPLE-buffered (slots 24KB, 72KB total; 2 blocks/CU); stage 2 tiles ahead;
// tile-top s_waitcnt vmcnt(6) lgkmcnt(0) (6 loads/stage, 12 outstanding); vmcnt(0) last.
__global__ __launch_bounds__(256, 2) void k_attn(const u16* __restrict__ qn,
                                                 const u16* __restrict__ kn,
                                                 const u16* __restrict__ vnT,
                                                 const u16* __restrict__ gact,
                                                 const float* __restrict__ ls_iaw,
                                                 const float* __restrict__ ls_hws,
                                                 u16* __restrict__ pre_out) {
  extern __shared__ char smem[];
  u16* KsB = (u16*)smem;                 // [3][64 k][64 dk]   slot stride 4096 u16
  u16* VsB = (u16*)(smem + 24576);       // [3][128 d][64 k']  slot stride 8192 u16
  u16* Os = (u16*)smem;                  // epilogue reuse: [128 q][132 d] 33.8KB

  const int tid = threadIdx.x, lane = tid & 63, wid = tid >> 6;
  const int bid = blockIdx.y * 16 + blockIdx.x;
  const int bh = (bid & 7) * 4 + ((bid >> 3) & 3);
  const int n0 = (bid >> 5) * 128;
  const int h = bh & 15;
  const int l31 = lane & 31, L = lane >> 5, rb = l31 & 7;
  const float r = 1.f / (__expf(ls_iaw[h]) + 1.f);
  const float c1 = 1.f - r;
  const float whs = __expf(ls_hws[h]);

  const int wq = wid * 32;
  const u16* qrow = qn + ((size_t)bh * 2048 + n0 + wq + l31) * 64;
  u16x8 qf[4];
#pragma unroll
  for (int c = 0; c < 4; c++) qf[c] = *(const u16x8*)(qrow + c * 16 + L * 8);

  f32x16 acc[4] = {};  // acc[dt]: D[d = dt*32 + (reg&3)+8*(reg>>2)+4L][q = l31]
  const u16* kbase = kn + (size_t)bh * 2048 * 64;
  const u16* vbase = vnT + (size_t)bh * 128 * 2048;

  int ks_goff[2];
#pragma unroll
  for (int i = 0; i < 2; i++) {
    int row = wid * 16 + i * 8 + (lane >> 3);
    ks_goff[i] = row * 64 + (((lane & 7) ^ (row & 7)) << 3);
  }
  int vs_goff[4];
#pragma unroll
  for (int i = 0; i < 4; i++) {
    int row = wid * 32 + i * 8 + (lane >> 3);
    vs_goff[i] = row * 2048 + (((lane & 7) ^ (row & 7)) << 3);
  }

  // prologue: stage tile 0 -> slot 0, tile 1 -> slot 1
  {
    u16* KsC0 = KsB + wid * 1024;
    u16* VsC0 = VsB + wid * 2048;
#pragma unroll
    for (int i = 0; i < 2; i++) gload_lds16(kbase + ks_goff[i], KsC0 + i * 512);
#pragma unroll
    for (int i = 0; i < 4; i++) gload_lds16(vbase + vs_goff[i], VsC0 + i * 512);
    u16* KsC1 = KsB + 4096 + wid * 1024;
    u16* VsC1 = VsB + 8192 + wid * 2048;
#pragma unroll
    for (int i = 0; i < 2; i++) gload_lds16(kbase + (size_t)64 * 64 + ks_goff[i], KsC1 + i * 512);
#pragma unroll
    for (int i = 0; i < 4; i++) gload_lds16(vbase + (size_t)vs_goff[i] + 64, VsC1 + i * 512);
  }

  int s = 0;
  for (int t = 0; t < 32; t++) {
    if (t < 31) {
      asm volatile("s_waitcnt vmcnt(6) lgkmcnt(0)" ::: "memory");
    } else {
      asm volatile("s_waitcnt vmcnt(0) lgkmcnt(0)" ::: "memory");
    }
    __builtin_amdgcn_s_barrier();
    asm volatile("" ::: "memory");

    if (t + 2 < 32) {
      const int s2 = (s + 2 >= 3) ? s - 1 : s + 2;
      const int kv0 = (t + 2) * 64;
      u16* KsC2 = KsB + s2 * 4096 + wid * 1024;
      u16* VsC2 = VsB + s2 * 8192 + wid * 2048;
#pragma unroll
      for (int i = 0; i < 2; i++) gload_lds16(kbase + (size_t)kv0 * 64 + ks_goff[i], KsC2 + i * 512);
#pragma unroll
      for (int i = 0; i < 4; i++) gload_lds16(vbase + (size_t)vs_goff[i] + kv0, VsC2 + i * 512);
    }

    const u16* KsC = KsB + s * 4096;
    const u16* VsC = VsB + s * 8192;

    f32x16 sT0 = {}, sT1 = {};
    __builtin_amdgcn_s_setprio(1);
#pragma unroll
    for (int c = 0; c < 4; c++) {
      u16x8 kf0 = *(const u16x8*)(KsC + (0 + l31) * 64 + (((2 * c + L) ^ rb) << 3));
      u16x8 kf1 = *(const u16x8*)(KsC + (32 + l31) * 64 + (((2 * c + L) ^ rb) << 3));
      sT0 = mfma32(kf0, qf[c], sT0);
      sT1 = mfma32(kf1, qf[c], sT1);
    }
    __builtin_amdgcn_s_setprio(0);

    uint32_t w[2][4][2];
#pragma unroll
    for (int m = 0; m < 4; m++)
#pragma unroll
      for (int p = 0; p < 2; p++) {
        float a0 = fmaxf(0.f, fmaf(r, sT0[4 * m + 2 * p], c1));
        float a1 = fmaxf(0.f, fmaf(r, sT0[4 * m + 2 * p + 1], c1));
        float b0 = fmaxf(0.f, fmaf(r, sT1[4 * m + 2 * p], c1));
        float b1 = fmaxf(0.f, fmaf(r, sT1[4 * m + 2 * p + 1], c1));
        w[0][m][p] = (uint32_t)f2bf(a0 * a0) | ((uint32_t)f2bf(a1 * a1) << 16);
        w[1][m][p] = (uint32_t)f2bf(b0 * b0) | ((uint32_t)f2bf(b1 * b1) << 16);
      }

    __builtin_amdgcn_s_setprio(1);
#pragma unroll
    for (int kt = 0; kt < 2; kt++)
#pragma unroll
      for (int pair = 0; pair < 2; pair++) {
        i32x4 pw;
        pw[0] = (int)w[kt][2 * pair][0];
        pw[1] = (int)w[kt][2 * pair][1];
        pw[2] = (int)w[kt][2 * pair + 1][0];
        pw[3] = (int)w[kt][2 * pair + 1][1];
        u16x8 pf = __builtin_bit_cast(u16x8, pw);
        const int chunk = 4 * kt + 2 * pair + L;
#pragma unroll
        for (int dt = 0; dt < 4; dt++) {
          u16x8 vf = *(const u16x8*)(VsC + (dt * 32 + l31) * 64 + ((chunk ^ rb) << 3));
          acc[dt] = mfma32(vf, pf, acc[dt]);
        }
      }
    __builtin_amdgcn_s_setprio(0);
    s = (s + 1 >= 3) ? 0 : s + 1;
  }

  float ss = 0.f;
#pragma unroll
  for (int dt = 0; dt < 4; dt++)
#pragma unroll
    for (int e = 0; e < 16; e++) { float x = acc[dt][e]; ss += x * x; }
  ss += __shfl_xor(ss, 32);
  float nn = sqrtf(ss);
  float scale = tanhf(nn) / fmaxf(nn, 1e-12f) * whs;

  __syncthreads();

  const int q = wq + l31;
  const size_t grow = ((size_t)bh * 2048 + n0 + q) * 128;
#pragma unroll
  for (int dt = 0; dt < 4; dt++)
#pragma unroll
    for (int m = 0; m < 4; m++) {
      const int d = dt * 32 + 8 * m + 4 * L;
      ushort4 gv = *(const ushort4*)(gact + grow + d);
      ushort4 o;
      o.x = f2bf(acc[dt][4 * m + 0] * scale * bf2f(gv.x));
      o.y = f2bf(acc[dt][4 * m + 1] * scale * bf2f(gv.y));
      o.z = f2bf(acc[dt][4 * m + 2] * scale * bf2f(gv.z));
      o.w = f2bf(acc[dt][4 * m + 3] * scale * bf2f(gv.w));
      *(ushort4*)(Os + q * 132 + d) = o;
    }
  __syncthreads();

  const int orow = tid >> 1, oc0 = (tid & 1) * 64;
  const size_t obase = ((size_t)(bh >> 4) * 2048 + n0 + orow) * 2048 + (size_t)h * 128 + oc0;
#pragma unroll
  for (int j = 0; j < 16; j++) {
    ushort4 v = *(const ushort4*)(Os + orow * 132 + oc0 + 4 * j);
    *(ushort4*)(pre_out + obase + 4 * j) = v;
  }
}

extern "C" void kernel_launch(void* const* d_in, const int* in_sizes, int n_in,
                              void* d_out, int out_size, void* d_ws, size_t ws_size,
                              hipStream_t stream) {
  (void)in_sizes; (void)n_in; (void)out_size; (void)ws_size;
  const float* tokens = (const float*)d_in[0];
  const float* Wqg = (const float*)d_in[1];
  const float* Wkv = (const float*)d_in[2];
  const float* Wo = (const float*)d_in[3];
  const float* ls_iaw = (const float*)d_in[4];
  const float* ls_hws = (const float*)d_in[5];
  float* out = (float*)d_out;
  char* ws = (char*)d_ws;

  // workspace layout (phased aliasing, total 109 MB):
  u16* WoT = (u16*)(ws + 0);                     // 8,388,608 B
  char* regA = ws + 8388608;                     // 50,331,648 B
  u16* tok_bf = (u16*)(regA);                    // phase A-B (16.8MB)
  u16* WqgkvT = (u16*)(regA + 16777216);         // phase A-B (25.2MB) [6144][2048]
  u16* qn = (u16*)(regA);                        // phase C-D
  u16* kn = (u16*)(regA + 8388608);
  u16* vnT = (u16*)(regA + 16777216);
  u16* gact = (u16*)(regA + 33554432);
  char* regB = ws + 58720256;                    // 50,331,648 B
  u16* qgkv_raw = (u16*)(regB);                  // phase B-C [4096][6144]
  u16* pre_out = (u16*)(regB);                   // phase D-E

  k_cvt<<<4096, 256, 0, stream>>>(tokens, tok_bf, 8388608);
  k_cvtT<<<dim3(96, 64), 256, 0, stream>>>(Wqg, WqgkvT, 2048, 3072);
  k_cvtT<<<dim3(96, 64), 256, 0, stream>>>(Wkv, WqgkvT + (size_t)3072 * 2048, 2048, 3072);
  k_cvtT<<<dim3(64, 64), 256, 0, stream>>>(Wo, WoT, 2048, 2048);

  // merged projection: 256x384 tile, grid 256 = 1 exact round, 120KB LDS triple-buffer
  k_gemmP2<<<256, 512, 122880, stream>>>(tok_bf, WqgkvT, qgkv_raw, 6144, 2048);

  k_norm<<<dim3(32, 32), 256, 0, stream>>>(qgkv_raw, qn, kn, vnT, gact);

  // attn: 72KB LDS (3-slot K/V), 2 blocks/CU
  k_attn<<<dim3(16, 32), 256, 73728, stream>>>(qn, kn, vnT, gact, ls_iaw, ls_hws, pre_out);

  // final projection: 128x256 tile, grid 256 = 1 exact round, 144KB LDS triple-buffer
  k_gemmU<2, 1><<<256, 512, 147456, stream>>>(pre_out, WoT, out, 2048, 2048);
}